// Round 1
// baseline (857.631 us; speedup 1.0000x reference)
//
#include <hip/hip_runtime.h>
#include <math.h>

#define N_ATOMS 16384
#define APC 64
#define N_CONF 256
#define N_MOL 64
#define DEG 32
#define NEDGE (N_ATOMS * DEG)
#define H 128
#define G 50
#define NL 6
#define TP 4096          // table points
#define CUTOFF 10.0f

__device__ __forceinline__ float ssp_f(float x) {
  // softplus(x) - log(2), numerically stable
  return fmaxf(x, 0.f) + log1pf(expf(-fabsf(x))) - 0.69314718055994531f;
}

// h[n][c] = emb[z[n]][c]
__global__ __launch_bounds__(256) void k_embed(const int* __restrict__ z,
                                               const float* __restrict__ emb,
                                               float* __restrict__ h) {
  int i = blockIdx.x * 256 + threadIdx.x;   // i < N_ATOMS*H
  int n = i >> 7, c = i & 127;
  h[i] = emb[z[n] * H + c];
}

// per-edge: distance -> table index + fraction
__global__ __launch_bounds__(256) void k_edge_prep(const float* __restrict__ pos,
                                                   const int* __restrict__ esrc,
                                                   const int* __restrict__ etgt,
                                                   int* __restrict__ tidx,
                                                   float* __restrict__ tfrac) {
  int e = blockIdx.x * 256 + threadIdx.x;
  int r = esrc[e], c = etgt[e];
  float dx = pos[r * 3 + 0] - pos[c * 3 + 0];
  float dy = pos[r * 3 + 1] - pos[c * 3 + 1];
  float dz = pos[r * 3 + 2] - pos[c * 3 + 2];
  float d = sqrtf(dx * dx + dy * dy + dz * dz);
  float u = d * ((float)(TP - 1) / CUTOFF);
  int i = (int)u;
  if (i > TP - 2) i = TP - 2;
  tidx[e] = i;
  tfrac[e] = u - (float)i;
}

// Build filter table T[l][p][c] = ( ssp(gauss(d_p)@w1 + b1) @ w2 + b2 ) * Ccut(d_p)
// grid: NL*TP blocks of 128 threads
__global__ void k_table(const float* __restrict__ w1, const float* __restrict__ b1,
                        const float* __restrict__ w2, const float* __restrict__ b2,
                        float* __restrict__ T) {
  int wg = blockIdx.x;
  int l = wg >> 12;          // TP = 4096 = 2^12
  int p = wg & (TP - 1);
  int tid = threadIdx.x;     // 128
  float d = (float)p * (CUTOFF / (float)(TP - 1));
  __shared__ float g[G];
  __shared__ float S[H];
  const float gspace = CUTOFF / (float)(G - 1);
  const float coeff = -0.5f / (gspace * gspace);
  if (tid < G) {
    float x = d - (float)tid * gspace;
    g[tid] = expf(coeff * x * x);
  }
  __syncthreads();
  const float* W1 = w1 + l * G * H;
  float s = b1[l * H + tid];
  #pragma unroll 5
  for (int i = 0; i < G; i++) s += g[i] * W1[i * H + tid];
  S[tid] = ssp_f(s);
  __syncthreads();
  const float* W2 = w2 + l * H * H;
  float o = b2[l * H + tid];
  #pragma unroll 8
  for (int j = 0; j < H; j++) o += S[j] * W2[j * H + tid];
  float Cc = 0.5f * (cosf(d * (3.14159265358979f / CUTOFF)) + 1.f);
  T[((size_t)l * TP + p) * H + tid] = o * Cc;
}

// plain GEMM: C[M x 128] = A[M x 128] @ B[128 x 128]
// 32 rows per block, 256 threads; thread -> 4 rows x 4 cols
__global__ __launch_bounds__(256) void k_gemm(const float* __restrict__ A,
                                              const float* __restrict__ B,
                                              float* __restrict__ C) {
  const int rb = blockIdx.x * 32;
  const int rl = (threadIdx.x >> 5) << 2;
  const int c0 = (threadIdx.x & 31) << 2;
  float acc[4][4] = {};
  for (int k = 0; k < H; k += 4) {
    float4 bv[4];
    #pragma unroll
    for (int kk = 0; kk < 4; kk++)
      bv[kk] = *(const float4*)&B[(k + kk) * H + c0];
    #pragma unroll
    for (int i = 0; i < 4; i++) {
      float4 a = *(const float4*)&A[(size_t)(rb + rl + i) * H + k];
      float av[4] = {a.x, a.y, a.z, a.w};
      #pragma unroll
      for (int kk = 0; kk < 4; kk++) {
        float bb[4] = {bv[kk].x, bv[kk].y, bv[kk].z, bv[kk].w};
        #pragma unroll
        for (int j = 0; j < 4; j++) acc[i][j] += av[kk] * bb[j];
      }
    }
  }
  #pragma unroll
  for (int i = 0; i < 4; i++)
    #pragma unroll
    for (int j = 0; j < 4; j++)
      C[(size_t)(rb + rl + i) * H + c0 + j] = acc[i][j];
}

// fused: t = ssp(A@B1 + bias1);  res = t@B2 + bias2;
// residual==1: out += res (out is h), else out = res
__global__ __launch_bounds__(256) void k_fused2(const float* __restrict__ A,
                                                const float* __restrict__ B1,
                                                const float* __restrict__ bias1,
                                                const float* __restrict__ B2,
                                                const float* __restrict__ bias2,
                                                float* __restrict__ out,
                                                int residual) {
  __shared__ float tT[32][132];
  const int rb = blockIdx.x * 32;
  const int rl = (threadIdx.x >> 5) << 2;
  const int c0 = (threadIdx.x & 31) << 2;
  float acc[4][4] = {};
  for (int k = 0; k < H; k += 4) {
    float4 bv[4];
    #pragma unroll
    for (int kk = 0; kk < 4; kk++)
      bv[kk] = *(const float4*)&B1[(k + kk) * H + c0];
    #pragma unroll
    for (int i = 0; i < 4; i++) {
      float4 a = *(const float4*)&A[(size_t)(rb + rl + i) * H + k];
      float av[4] = {a.x, a.y, a.z, a.w};
      #pragma unroll
      for (int kk = 0; kk < 4; kk++) {
        float bb[4] = {bv[kk].x, bv[kk].y, bv[kk].z, bv[kk].w};
        #pragma unroll
        for (int j = 0; j < 4; j++) acc[i][j] += av[kk] * bb[j];
      }
    }
  }
  #pragma unroll
  for (int i = 0; i < 4; i++)
    #pragma unroll
    for (int j = 0; j < 4; j++)
      tT[rl + i][c0 + j] = ssp_f(acc[i][j] + bias1[c0 + j]);
  __syncthreads();
  float acc2[4][4] = {};
  for (int k = 0; k < H; k += 4) {
    float4 bv[4];
    #pragma unroll
    for (int kk = 0; kk < 4; kk++)
      bv[kk] = *(const float4*)&B2[(k + kk) * H + c0];
    #pragma unroll
    for (int i = 0; i < 4; i++) {
      float4 a = *(const float4*)&tT[rl + i][k];
      float av[4] = {a.x, a.y, a.z, a.w};
      #pragma unroll
      for (int kk = 0; kk < 4; kk++) {
        float bb[4] = {bv[kk].x, bv[kk].y, bv[kk].z, bv[kk].w};
        #pragma unroll
        for (int j = 0; j < 4; j++) acc2[i][j] += av[kk] * bb[j];
      }
    }
  }
  #pragma unroll
  for (int i = 0; i < 4; i++) {
    size_t base = (size_t)(rb + rl + i) * H + c0;
    #pragma unroll
    for (int j = 0; j < 4; j++) {
      float r = acc2[i][j] + bias2[c0 + j];
      if (residual) r += out[base + j];
      out[base + j] = r;
    }
  }
}

// agg[n][c] = sum_{k<32} lerp(T, idx_e, frac_e)[c] * xf[src_e][c],  e = n*32+k
// 2 atoms per block (256 threads)
__global__ __launch_bounds__(256) void k_edge_agg(const float* __restrict__ xf,
                                                  const float* __restrict__ T,
                                                  const int* __restrict__ tidx,
                                                  const float* __restrict__ tfrac,
                                                  const int* __restrict__ esrc,
                                                  float* __restrict__ agg) {
  int atom = blockIdx.x * 2 + (threadIdx.x >> 7);
  int c = threadIdx.x & 127;
  int ebase = atom * DEG;
  float acc = 0.f;
  #pragma unroll 4
  for (int k = 0; k < DEG; k++) {
    int e = ebase + k;
    int idx = tidx[e];
    float f = tfrac[e];
    int r = esrc[e];
    float t0 = T[(size_t)idx * H + c];
    float t1 = T[(size_t)(idx + 1) * H + c];
    float wf = t0 + f * (t1 - t0);
    acc += wf * xf[(size_t)r * H + c];
  }
  agg[(size_t)atom * H + c] = acc;
}

// per-mol pooling (256 contiguous atoms) + head MLP
__global__ __launch_bounds__(256) void k_pool_head(const float* __restrict__ h2,
                                                   const float* __restrict__ hw1,
                                                   const float* __restrict__ hb1,
                                                   const float* __restrict__ hw2,
                                                   const float* __restrict__ hb2,
                                                   float* __restrict__ outp) {
  int m = blockIdx.x;
  int c = threadIdx.x & 127;
  int half = threadIdx.x >> 7;
  __shared__ float mol2[2][128];
  __shared__ float q[64];
  const float* base = h2 + (size_t)m * 256 * H;
  float s = 0.f;
  for (int a = half; a < 256; a += 2) s += base[(size_t)a * H + c];
  mol2[half][c] = s;
  __syncthreads();
  if (threadIdx.x < 64) {
    int j = threadIdx.x;
    float qq = hb1[j];
    #pragma unroll 8
    for (int cc = 0; cc < H; cc++) qq += (mol2[0][cc] + mol2[1][cc]) * hw1[cc * 64 + j];
    q[j] = ssp_f(qq);
  }
  __syncthreads();
  if (threadIdx.x == 0) {
    float o = hb2[0];
    for (int j = 0; j < 64; j++) o += q[j] * hw2[j];
    outp[m] = o;
  }
}

extern "C" void kernel_launch(void* const* d_in, const int* in_sizes, int n_in,
                              void* d_out, int out_size, void* d_ws, size_t ws_size,
                              hipStream_t stream) {
  const int*   z       = (const int*)d_in[0];
  const float* pos     = (const float*)d_in[1];
  const int*   eidx    = (const int*)d_in[2];   // [2, E]: src then tgt
  const float* emb     = (const float*)d_in[5];
  const float* mlp_w1  = (const float*)d_in[6];
  const float* mlp_b1  = (const float*)d_in[7];
  const float* mlp_w2  = (const float*)d_in[8];
  const float* mlp_b2  = (const float*)d_in[9];
  const float* cf_w1   = (const float*)d_in[10];
  const float* cf_w2   = (const float*)d_in[11];
  const float* cf_b2   = (const float*)d_in[12];
  const float* int_w   = (const float*)d_in[13];
  const float* int_b   = (const float*)d_in[14];
  const float* out_w1  = (const float*)d_in[15];
  const float* out_b1  = (const float*)d_in[16];
  const float* out_w2  = (const float*)d_in[17];
  const float* out_b2  = (const float*)d_in[18];
  const float* head_w1 = (const float*)d_in[19];
  const float* head_b1 = (const float*)d_in[20];
  const float* head_w2 = (const float*)d_in[21];
  const float* head_b2 = (const float*)d_in[22];

  float* ws   = (float*)d_ws;
  float* T    = ws;                         // NL*TP*H = 3,145,728 floats
  float* h    = T + (size_t)NL * TP * H;    // 2,097,152
  float* xf   = h + (size_t)N_ATOMS * H;    // 2,097,152
  float* agg  = xf + (size_t)N_ATOMS * H;   // 2,097,152
  float* frac = agg + (size_t)N_ATOMS * H;  // 524,288
  int*   tidx = (int*)(frac + NEDGE);       // 524,288 ints

  k_embed<<<(N_ATOMS * H) / 256, 256, 0, stream>>>(z, emb, h);
  k_edge_prep<<<NEDGE / 256, 256, 0, stream>>>(pos, eidx, eidx + NEDGE, tidx, frac);
  k_table<<<NL * TP, 128, 0, stream>>>(mlp_w1, mlp_b1, mlp_w2, mlp_b2, T);

  for (int l = 0; l < NL; l++) {
    k_gemm<<<N_ATOMS / 32, 256, 0, stream>>>(h, cf_w1 + (size_t)l * H * H, xf);
    k_edge_agg<<<N_ATOMS / 2, 256, 0, stream>>>(xf, T + (size_t)l * TP * H,
                                                tidx, frac, eidx, agg);
    k_fused2<<<N_ATOMS / 32, 256, 0, stream>>>(agg, cf_w2 + (size_t)l * H * H,
                                               cf_b2 + (size_t)l * H,
                                               int_w + (size_t)l * H * H,
                                               int_b + (size_t)l * H, h, 1);
  }

  // readout: h2 = ssp(h@out_w1+b1)@out_w2 + b2  -> reuse xf buffer
  k_fused2<<<N_ATOMS / 32, 256, 0, stream>>>(h, out_w1, out_b1, out_w2, out_b2, xf, 0);
  k_pool_head<<<N_MOL, 256, 0, stream>>>(xf, head_w1, head_b1, head_w2, head_b2,
                                         (float*)d_out);
}

// Round 2
// 557.496 us; speedup vs baseline: 1.5384x; 1.5384x over previous
//
#include <hip/hip_runtime.h>
#include <math.h>

#define N_ATOMS 16384
#define APC 64
#define N_CONF 256
#define N_MOL 64
#define DEG 32
#define NEDGE (N_ATOMS * DEG)
#define H 128
#define G 50
#define NL 6
#define TP 1024          // table points
#define CUTOFF 10.0f

__device__ __forceinline__ float ssp_f(float x) {
  // softplus(x) - log(2), numerically stable
  return fmaxf(x, 0.f) + log1pf(expf(-fabsf(x))) - 0.69314718055994531f;
}

// h[n][c] = emb[z[n]][c]
__global__ __launch_bounds__(256) void k_embed(const int* __restrict__ z,
                                               const float* __restrict__ emb,
                                               float* __restrict__ h) {
  int i = blockIdx.x * 256 + threadIdx.x;
  int n = i >> 7, c = i & 127;
  h[i] = emb[z[n] * H + c];
}

// per-edge: distance -> packed (table index | src_local<<16) + fraction
__global__ __launch_bounds__(256) void k_edge_prep(const float* __restrict__ pos,
                                                   const int* __restrict__ esrc,
                                                   const int* __restrict__ etgt,
                                                   int* __restrict__ pk,
                                                   float* __restrict__ tfrac) {
  int e = blockIdx.x * 256 + threadIdx.x;
  int r = esrc[e], c = etgt[e];
  float dx = pos[r * 3 + 0] - pos[c * 3 + 0];
  float dy = pos[r * 3 + 1] - pos[c * 3 + 1];
  float dz = pos[r * 3 + 2] - pos[c * 3 + 2];
  float d = sqrtf(dx * dx + dy * dy + dz * dz);
  float u = d * ((float)(TP - 1) / CUTOFF);
  int i = (int)u;
  if (i > TP - 2) i = TP - 2;
  pk[e] = i | ((r & (APC - 1)) << 16);
  tfrac[e] = u - (float)i;
}

// Build filter table T[l][p][c]; 2 points per 256-thread block
__global__ __launch_bounds__(256) void k_table(const float* __restrict__ w1,
                                               const float* __restrict__ b1,
                                               const float* __restrict__ w2,
                                               const float* __restrict__ b2,
                                               float* __restrict__ T) {
  const int l = blockIdx.x >> 9;           // TP/2 = 512 blocks per layer
  const int grp = threadIdx.x >> 7;        // 0/1 -> point
  const int c = threadIdx.x & 127;
  const int p = (blockIdx.x & 511) * 2 + grp;
  const float d = (float)p * (CUTOFF / (float)(TP - 1));
  __shared__ float g2[2][64];
  __shared__ float S2[2][128];
  const float gspace = CUTOFF / (float)(G - 1);
  const float coeff = -0.5f / (gspace * gspace);
  if (c < G) {
    float x = d - (float)c * gspace;
    g2[grp][c] = expf(coeff * x * x);
  }
  __syncthreads();
  const float* W1 = w1 + l * G * H;
  float s = b1[l * H + c];
  #pragma unroll 5
  for (int i = 0; i < G; i++) s += g2[grp][i] * W1[i * H + c];
  S2[grp][c] = ssp_f(s);
  __syncthreads();
  const float* W2 = w2 + l * H * H;
  float o = b2[l * H + c];
  #pragma unroll 8
  for (int j = 0; j < H; j++) o += S2[grp][j] * W2[j * H + c];
  float Cc = 0.5f * (cosf(d * (3.14159265358979f / CUTOFF)) + 1.f);
  T[((size_t)l * TP + p) * H + c] = o * Cc;
}

// Per-conformer: stage h tile, xf = h @ W into LDS, then aggregate 2048 edges.
__global__ __launch_bounds__(256) void k_conf(const float* __restrict__ h,
                                              const float* __restrict__ W,
                                              const float* __restrict__ T,
                                              const int* __restrict__ pk,
                                              const float* __restrict__ tfrac,
                                              float* __restrict__ agg) {
  __shared__ float hs[64][132];
  __shared__ float xfs[64][132];
  __shared__ int   pks[2048];
  __shared__ float frs[2048];
  const int conf = blockIdx.x;
  const int tid = threadIdx.x;
  const size_t rowbase = (size_t)conf * 64;
  // stage h tile (coalesced float4)
  #pragma unroll
  for (int i = 0; i < 8; i++) {
    int flat = i * 1024 + tid * 4;
    int r = flat >> 7, c = flat & 127;
    *(float4*)&hs[r][c] = *(const float4*)&h[(rowbase + r) * H + c];
  }
  // stage edge metadata
  const int ebase0 = conf * 2048;
  #pragma unroll
  for (int i = 0; i < 8; i++) {
    pks[i * 256 + tid] = pk[ebase0 + i * 256 + tid];
    frs[i * 256 + tid] = tfrac[ebase0 + i * 256 + tid];
  }
  __syncthreads();
  // GEMM: xfs = hs @ W   (thread: 8 rows x 4 cols)
  const int r0 = (tid >> 5) * 8;
  const int c0 = (tid & 31) * 4;
  {
    float acc[8][4] = {};
    #pragma unroll 2
    for (int k = 0; k < H; k += 4) {
      float4 bv[4];
      #pragma unroll
      for (int kk = 0; kk < 4; kk++)
        bv[kk] = *(const float4*)&W[(k + kk) * H + c0];
      #pragma unroll
      for (int i = 0; i < 8; i++) {
        float4 a = *(const float4*)&hs[r0 + i][k];
        float av[4] = {a.x, a.y, a.z, a.w};
        #pragma unroll
        for (int kk = 0; kk < 4; kk++) {
          float bb[4] = {bv[kk].x, bv[kk].y, bv[kk].z, bv[kk].w};
          #pragma unroll
          for (int j = 0; j < 4; j++) acc[i][j] += av[kk] * bb[j];
        }
      }
    }
    #pragma unroll
    for (int i = 0; i < 8; i++)
      #pragma unroll
      for (int j = 0; j < 4; j++)
        xfs[r0 + i][c0 + j] = acc[i][j];
  }
  __syncthreads();
  // edge aggregation: 8 atoms/pass, 32 lanes (4 ch each) per atom
  const int ag = tid >> 5;
  #pragma unroll
  for (int pass = 0; pass < 8; pass++) {
    int a = pass * 8 + ag;
    int eb = a * DEG;
    float4 acc = {0.f, 0.f, 0.f, 0.f};
    #pragma unroll 4
    for (int e = 0; e < DEG; e++) {
      int pv = pks[eb + e];
      float f = frs[eb + e];
      int idx = pv & 0xFFFF;
      int sl = pv >> 16;
      float4 t0 = *(const float4*)&T[(size_t)idx * H + c0];
      float4 t1 = *(const float4*)&T[(size_t)(idx + 1) * H + c0];
      float4 xv = *(const float4*)&xfs[sl][c0];
      acc.x += (t0.x + f * (t1.x - t0.x)) * xv.x;
      acc.y += (t0.y + f * (t1.y - t0.y)) * xv.y;
      acc.z += (t0.z + f * (t1.z - t0.z)) * xv.z;
      acc.w += (t0.w + f * (t1.w - t0.w)) * xv.w;
    }
    *(float4*)&agg[(rowbase + a) * H + c0] = acc;
  }
}

// 2-GEMM node MLP: out = (residual? hio : 0) + ssp(A@W1+b1)@W2 + b2
__global__ __launch_bounds__(256) void k_node2(const float* __restrict__ A,
                                               const float* __restrict__ W1,
                                               const float* __restrict__ b1,
                                               const float* __restrict__ W2,
                                               const float* __restrict__ b2,
                                               float* __restrict__ hio,
                                               int residual) {
  __shared__ float As[64][132];
  __shared__ float ts[64][132];
  const int rb = blockIdx.x * 64;
  const int tid = threadIdx.x;
  #pragma unroll
  for (int i = 0; i < 8; i++) {
    int flat = i * 1024 + tid * 4;
    int r = flat >> 7, c = flat & 127;
    *(float4*)&As[r][c] = *(const float4*)&A[(size_t)(rb + r) * H + c];
  }
  __syncthreads();
  const int r0 = (tid >> 5) * 8;
  const int c0 = (tid & 31) * 4;
  {
    float acc[8][4] = {};
    #pragma unroll 2
    for (int k = 0; k < H; k += 4) {
      float4 bv[4];
      #pragma unroll
      for (int kk = 0; kk < 4; kk++)
        bv[kk] = *(const float4*)&W1[(k + kk) * H + c0];
      #pragma unroll
      for (int i = 0; i < 8; i++) {
        float4 a = *(const float4*)&As[r0 + i][k];
        float av[4] = {a.x, a.y, a.z, a.w};
        #pragma unroll
        for (int kk = 0; kk < 4; kk++) {
          float bb[4] = {bv[kk].x, bv[kk].y, bv[kk].z, bv[kk].w};
          #pragma unroll
          for (int j = 0; j < 4; j++) acc[i][j] += av[kk] * bb[j];
        }
      }
    }
    #pragma unroll
    for (int i = 0; i < 8; i++)
      #pragma unroll
      for (int j = 0; j < 4; j++)
        ts[r0 + i][c0 + j] = ssp_f(acc[i][j] + b1[c0 + j]);
  }
  __syncthreads();
  {
    float acc[8][4] = {};
    #pragma unroll 2
    for (int k = 0; k < H; k += 4) {
      float4 bv[4];
      #pragma unroll
      for (int kk = 0; kk < 4; kk++)
        bv[kk] = *(const float4*)&W2[(k + kk) * H + c0];
      #pragma unroll
      for (int i = 0; i < 8; i++) {
        float4 a = *(const float4*)&ts[r0 + i][k];
        float av[4] = {a.x, a.y, a.z, a.w};
        #pragma unroll
        for (int kk = 0; kk < 4; kk++) {
          float bb[4] = {bv[kk].x, bv[kk].y, bv[kk].z, bv[kk].w};
          #pragma unroll
          for (int j = 0; j < 4; j++) acc[i][j] += av[kk] * bb[j];
        }
      }
    }
    #pragma unroll
    for (int i = 0; i < 8; i++) {
      size_t base = (size_t)(rb + r0 + i) * H + c0;
      #pragma unroll
      for (int j = 0; j < 4; j++) {
        float r = acc[i][j] + b2[c0 + j];
        if (residual) r += hio[base + j];
        hio[base + j] = r;
      }
    }
  }
}

// per-mol pooling (256 contiguous atoms) + head MLP
__global__ __launch_bounds__(256) void k_pool_head(const float* __restrict__ h2,
                                                   const float* __restrict__ hw1,
                                                   const float* __restrict__ hb1,
                                                   const float* __restrict__ hw2,
                                                   const float* __restrict__ hb2,
                                                   float* __restrict__ outp) {
  int m = blockIdx.x;
  int c = threadIdx.x & 127;
  int half = threadIdx.x >> 7;
  __shared__ float mol2[2][128];
  __shared__ float q[64];
  const float* base = h2 + (size_t)m * 256 * H;
  float s = 0.f;
  for (int a = half; a < 256; a += 2) s += base[(size_t)a * H + c];
  mol2[half][c] = s;
  __syncthreads();
  if (threadIdx.x < 64) {
    int j = threadIdx.x;
    float qq = hb1[j];
    #pragma unroll 8
    for (int cc = 0; cc < H; cc++) qq += (mol2[0][cc] + mol2[1][cc]) * hw1[cc * 64 + j];
    q[j] = ssp_f(qq);
  }
  __syncthreads();
  if (threadIdx.x == 0) {
    float o = hb2[0];
    for (int j = 0; j < 64; j++) o += q[j] * hw2[j];
    outp[m] = o;
  }
}

extern "C" void kernel_launch(void* const* d_in, const int* in_sizes, int n_in,
                              void* d_out, int out_size, void* d_ws, size_t ws_size,
                              hipStream_t stream) {
  const int*   z       = (const int*)d_in[0];
  const float* pos     = (const float*)d_in[1];
  const int*   eidx    = (const int*)d_in[2];   // [2, E]: src then tgt
  const float* emb     = (const float*)d_in[5];
  const float* mlp_w1  = (const float*)d_in[6];
  const float* mlp_b1  = (const float*)d_in[7];
  const float* mlp_w2  = (const float*)d_in[8];
  const float* mlp_b2  = (const float*)d_in[9];
  const float* cf_w1   = (const float*)d_in[10];
  const float* cf_w2   = (const float*)d_in[11];
  const float* cf_b2   = (const float*)d_in[12];
  const float* int_w   = (const float*)d_in[13];
  const float* int_b   = (const float*)d_in[14];
  const float* out_w1  = (const float*)d_in[15];
  const float* out_b1  = (const float*)d_in[16];
  const float* out_w2  = (const float*)d_in[17];
  const float* out_b2  = (const float*)d_in[18];
  const float* head_w1 = (const float*)d_in[19];
  const float* head_b1 = (const float*)d_in[20];
  const float* head_w2 = (const float*)d_in[21];
  const float* head_b2 = (const float*)d_in[22];

  float* ws   = (float*)d_ws;
  float* T    = ws;                         // NL*TP*H = 786,432 floats
  float* h    = T + (size_t)NL * TP * H;    // 2,097,152
  float* agg  = h + (size_t)N_ATOMS * H;    // 2,097,152
  float* h2   = agg + (size_t)N_ATOMS * H;  // 2,097,152
  float* frac = h2 + (size_t)N_ATOMS * H;   // 524,288
  int*   pk   = (int*)(frac + NEDGE);       // 524,288 ints

  k_embed<<<(N_ATOMS * H) / 256, 256, 0, stream>>>(z, emb, h);
  k_edge_prep<<<NEDGE / 256, 256, 0, stream>>>(pos, eidx, eidx + NEDGE, pk, frac);
  k_table<<<NL * (TP / 2), 256, 0, stream>>>(mlp_w1, mlp_b1, mlp_w2, mlp_b2, T);

  for (int l = 0; l < NL; l++) {
    k_conf<<<N_CONF, 256, 0, stream>>>(h, cf_w1 + (size_t)l * H * H,
                                       T + (size_t)l * TP * H, pk, frac, agg);
    k_node2<<<N_ATOMS / 64, 256, 0, stream>>>(agg, cf_w2 + (size_t)l * H * H,
                                              cf_b2 + (size_t)l * H,
                                              int_w + (size_t)l * H * H,
                                              int_b + (size_t)l * H, h, 1);
  }

  k_node2<<<N_ATOMS / 64, 256, 0, stream>>>(h, out_w1, out_b1, out_w2, out_b2, h2, 0);
  k_pool_head<<<N_MOL, 256, 0, stream>>>(h2, head_w1, head_b1, head_w2, head_b2,
                                         (float*)d_out);
}

// Round 3
// 481.263 us; speedup vs baseline: 1.7820x; 1.1584x over previous
//
#include <hip/hip_runtime.h>
#include <math.h>

#define N_ATOMS 16384
#define APC 64
#define N_CONF 256
#define N_MOL 64
#define DEG 32
#define NEDGE (N_ATOMS * DEG)
#define H 128
#define G 50
#define NL 6
#define TP 1024          // table points
#define CUTOFF 10.0f

typedef __attribute__((ext_vector_type(8))) short short8_t;
typedef __attribute__((ext_vector_type(4))) float f32x4;

__device__ __forceinline__ float ssp_f(float x) {
  return fmaxf(x, 0.f) + log1pf(expf(-fabsf(x))) - 0.69314718055994531f;
}

__device__ __forceinline__ unsigned short bf16_rne(float x) {
  unsigned u = __float_as_uint(x);
  unsigned r = u + 0x7FFF + ((u >> 16) & 1);
  return (unsigned short)(r >> 16);
}
__device__ __forceinline__ float bf16_to_f(unsigned short s) {
  return __uint_as_float(((unsigned)s) << 16);
}

// h[n][c] = emb[z[n]][c]
__global__ __launch_bounds__(256) void k_embed(const int* __restrict__ z,
                                               const float* __restrict__ emb,
                                               float* __restrict__ h) {
  int i = blockIdx.x * 256 + threadIdx.x;
  int n = i >> 7, c = i & 127;
  h[i] = emb[z[n] * H + c];
}

// per-edge: distance -> packed (table index | src_local<<16) + fraction
__global__ __launch_bounds__(256) void k_edge_prep(const float* __restrict__ pos,
                                                   const int* __restrict__ esrc,
                                                   const int* __restrict__ etgt,
                                                   int* __restrict__ pk,
                                                   float* __restrict__ tfrac) {
  int e = blockIdx.x * 256 + threadIdx.x;
  int r = esrc[e], c = etgt[e];
  float dx = pos[r * 3 + 0] - pos[c * 3 + 0];
  float dy = pos[r * 3 + 1] - pos[c * 3 + 1];
  float dz = pos[r * 3 + 2] - pos[c * 3 + 2];
  float d = sqrtf(dx * dx + dy * dy + dz * dz);
  float u = d * ((float)(TP - 1) / CUTOFF);
  int i = (int)u;
  if (i > TP - 2) i = TP - 2;
  pk[e] = i | ((r & (APC - 1)) << 16);
  tfrac[e] = u - (float)i;
}

// Build filter table T[l][p][c]; 2 points per 256-thread block
__global__ __launch_bounds__(256) void k_table(const float* __restrict__ w1,
                                               const float* __restrict__ b1,
                                               const float* __restrict__ w2,
                                               const float* __restrict__ b2,
                                               float* __restrict__ T) {
  const int l = blockIdx.x >> 9;
  const int grp = threadIdx.x >> 7;
  const int c = threadIdx.x & 127;
  const int p = (blockIdx.x & 511) * 2 + grp;
  const float d = (float)p * (CUTOFF / (float)(TP - 1));
  __shared__ float g2[2][64];
  __shared__ float S2[2][128];
  const float gspace = CUTOFF / (float)(G - 1);
  const float coeff = -0.5f / (gspace * gspace);
  if (c < G) {
    float x = d - (float)c * gspace;
    g2[grp][c] = expf(coeff * x * x);
  }
  __syncthreads();
  const float* W1 = w1 + l * G * H;
  float s = b1[l * H + c];
  #pragma unroll 5
  for (int i = 0; i < G; i++) s += g2[grp][i] * W1[i * H + c];
  S2[grp][c] = ssp_f(s);
  __syncthreads();
  const float* W2 = w2 + l * H * H;
  float o = b2[l * H + c];
  #pragma unroll 8
  for (int j = 0; j < H; j++) o += S2[grp][j] * W2[j * H + c];
  float Cc = 0.5f * (cosf(d * (3.14159265358979f / CUTOFF)) + 1.f);
  T[((size_t)l * TP + p) * H + c] = o * Cc;
}

// Per-conformer: stage h tile, xf = h @ W into LDS, then aggregate 2048 edges.
__global__ __launch_bounds__(256) void k_conf(const float* __restrict__ h,
                                              const float* __restrict__ W,
                                              const float* __restrict__ T,
                                              const int* __restrict__ pk,
                                              const float* __restrict__ tfrac,
                                              float* __restrict__ agg) {
  __shared__ float hs[64][132];
  __shared__ float xfs[64][132];
  __shared__ int   pks[2048];
  __shared__ float frs[2048];
  const int conf = blockIdx.x;
  const int tid = threadIdx.x;
  const size_t rowbase = (size_t)conf * 64;
  #pragma unroll
  for (int i = 0; i < 8; i++) {
    int flat = i * 1024 + tid * 4;
    int r = flat >> 7, c = flat & 127;
    *(float4*)&hs[r][c] = *(const float4*)&h[(rowbase + r) * H + c];
  }
  const int ebase0 = conf * 2048;
  #pragma unroll
  for (int i = 0; i < 8; i++) {
    pks[i * 256 + tid] = pk[ebase0 + i * 256 + tid];
    frs[i * 256 + tid] = tfrac[ebase0 + i * 256 + tid];
  }
  __syncthreads();
  const int r0 = (tid >> 5) * 8;
  const int c0 = (tid & 31) * 4;
  {
    float acc[8][4] = {};
    #pragma unroll 2
    for (int k = 0; k < H; k += 4) {
      float4 bv[4];
      #pragma unroll
      for (int kk = 0; kk < 4; kk++)
        bv[kk] = *(const float4*)&W[(k + kk) * H + c0];
      #pragma unroll
      for (int i = 0; i < 8; i++) {
        float4 a = *(const float4*)&hs[r0 + i][k];
        float av[4] = {a.x, a.y, a.z, a.w};
        #pragma unroll
        for (int kk = 0; kk < 4; kk++) {
          float bb[4] = {bv[kk].x, bv[kk].y, bv[kk].z, bv[kk].w};
          #pragma unroll
          for (int j = 0; j < 4; j++) acc[i][j] += av[kk] * bb[j];
        }
      }
    }
    #pragma unroll
    for (int i = 0; i < 8; i++)
      #pragma unroll
      for (int j = 0; j < 4; j++)
        xfs[r0 + i][c0 + j] = acc[i][j];
  }
  __syncthreads();
  const int ag = tid >> 5;
  #pragma unroll
  for (int pass = 0; pass < 8; pass++) {
    int a = pass * 8 + ag;
    int eb = a * DEG;
    float4 acc = {0.f, 0.f, 0.f, 0.f};
    #pragma unroll 4
    for (int e = 0; e < DEG; e++) {
      int pv = pks[eb + e];
      float f = frs[eb + e];
      int idx = pv & 0xFFFF;
      int sl = pv >> 16;
      float4 t0 = *(const float4*)&T[(size_t)idx * H + c0];
      float4 t1 = *(const float4*)&T[(size_t)(idx + 1) * H + c0];
      float4 xv = *(const float4*)&xfs[sl][c0];
      acc.x += (t0.x + f * (t1.x - t0.x)) * xv.x;
      acc.y += (t0.y + f * (t1.y - t0.y)) * xv.y;
      acc.z += (t0.z + f * (t1.z - t0.z)) * xv.z;
      acc.w += (t0.w + f * (t1.w - t0.w)) * xv.w;
    }
    *(float4*)&agg[(rowbase + a) * H + c0] = acc;
  }
}

// Pre-swizzle node-MLP weights into MFMA B-fragment order, bf16 hi/lo.
// g=0..11: (cf_w2,int_w) per layer; g=12: out_w1; g=13: out_w2
__global__ __launch_bounds__(256) void k_prep(const float* __restrict__ cf_w2,
                                              const float* __restrict__ int_w,
                                              const float* __restrict__ out_w1,
                                              const float* __restrict__ out_w2,
                                              short* __restrict__ PW) {
  int e = blockIdx.x * 256 + threadIdx.x;      // < 14*16384
  int g = e >> 14;
  int r = e & 16383;
  int k = r >> 7, n = r & 127;
  const float* src;
  if (g < 12) {
    int l = g >> 1;
    src = (g & 1) ? (int_w + l * 16384) : (cf_w2 + l * 16384);
  } else {
    src = (g == 12) ? out_w1 : out_w2;
  }
  float x = src[r];
  unsigned short hb = bf16_rne(x);
  unsigned short lb = bf16_rne(x - bf16_to_f(hb));
  int kb = k >> 5, quad = (k >> 3) & 3, j = k & 7;
  int nt = n >> 4, ln = n & 15;
  int lane = quad * 16 + ln;
  int off = ((kb * 8 + nt) * 64 + lane) * 8 + j;
  PW[(size_t)g * 32768 + off] = (short)hb;
  PW[(size_t)g * 32768 + 16384 + off] = (short)lb;
}

// Node MLP on matrix cores, bf16x3 split:
// out = (residual? hio : 0) + ssp(A@W1+b1)@W2 + b2
__global__ __launch_bounds__(256) void k_node2_mfma(
    const float* __restrict__ A, const short* __restrict__ pw1,
    const float* __restrict__ b1, const short* __restrict__ pw2,
    const float* __restrict__ b2, float* __restrict__ hio, int residual) {
  __shared__ __align__(16) short aH[32][136];
  __shared__ __align__(16) short aL[32][136];
  __shared__ __align__(16) short tH[32][136];
  __shared__ __align__(16) short tL[32][136];
  const int tid = threadIdx.x;
  const int rb = blockIdx.x * 32;

  // stage + split A tile (32 x 128 fp32 -> bf16 hi/lo in LDS)
  {
    int r = tid >> 3;
    int c = (tid & 7) * 16;
    const float* src = A + (size_t)(rb + r) * H + c;
    short hbuf[16], lbuf[16];
    #pragma unroll
    for (int q = 0; q < 4; q++) {
      float4 v = *(const float4*)(src + q * 4);
      float vv[4] = {v.x, v.y, v.z, v.w};
      #pragma unroll
      for (int u = 0; u < 4; u++) {
        unsigned short hb = bf16_rne(vv[u]);
        hbuf[q * 4 + u] = (short)hb;
        lbuf[q * 4 + u] = (short)bf16_rne(vv[u] - bf16_to_f(hb));
      }
    }
    *(short8_t*)&aH[r][c]     = *(short8_t*)&hbuf[0];
    *(short8_t*)&aH[r][c + 8] = *(short8_t*)&hbuf[8];
    *(short8_t*)&aL[r][c]     = *(short8_t*)&lbuf[0];
    *(short8_t*)&aL[r][c + 8] = *(short8_t*)&lbuf[8];
  }
  __syncthreads();

  const int lane = tid & 63;
  const int wid = tid >> 6;
  const int quad = lane >> 4;
  const int ln = lane & 15;
  const int col0 = wid * 32 + ln;

  // ---- GEMM1: t = ssp(A@W1 + b1) ----
  {
    f32x4 acc[2][2] = {};
    #pragma unroll
    for (int kb = 0; kb < 4; kb++) {
      int ko = kb * 32 + quad * 8;
      short8_t a0h = *(const short8_t*)&aH[ln][ko];
      short8_t a0l = *(const short8_t*)&aL[ln][ko];
      short8_t a1h = *(const short8_t*)&aH[16 + ln][ko];
      short8_t a1l = *(const short8_t*)&aL[16 + ln][ko];
      const short* pb = pw1 + ((kb * 8 + wid * 2) * 64 + lane) * 8;
      short8_t b0h = *(const short8_t*)pb;
      short8_t b0l = *(const short8_t*)(pb + 16384);
      short8_t b1h_ = *(const short8_t*)(pb + 512);
      short8_t b1l_ = *(const short8_t*)(pb + 16384 + 512);
      acc[0][0] = __builtin_amdgcn_mfma_f32_16x16x32_bf16(a0h, b0h, acc[0][0], 0, 0, 0);
      acc[0][0] = __builtin_amdgcn_mfma_f32_16x16x32_bf16(a0h, b0l, acc[0][0], 0, 0, 0);
      acc[0][0] = __builtin_amdgcn_mfma_f32_16x16x32_bf16(a0l, b0h, acc[0][0], 0, 0, 0);
      acc[0][1] = __builtin_amdgcn_mfma_f32_16x16x32_bf16(a0h, b1h_, acc[0][1], 0, 0, 0);
      acc[0][1] = __builtin_amdgcn_mfma_f32_16x16x32_bf16(a0h, b1l_, acc[0][1], 0, 0, 0);
      acc[0][1] = __builtin_amdgcn_mfma_f32_16x16x32_bf16(a0l, b1h_, acc[0][1], 0, 0, 0);
      acc[1][0] = __builtin_amdgcn_mfma_f32_16x16x32_bf16(a1h, b0h, acc[1][0], 0, 0, 0);
      acc[1][0] = __builtin_amdgcn_mfma_f32_16x16x32_bf16(a1h, b0l, acc[1][0], 0, 0, 0);
      acc[1][0] = __builtin_amdgcn_mfma_f32_16x16x32_bf16(a1l, b0h, acc[1][0], 0, 0, 0);
      acc[1][1] = __builtin_amdgcn_mfma_f32_16x16x32_bf16(a1h, b1h_, acc[1][1], 0, 0, 0);
      acc[1][1] = __builtin_amdgcn_mfma_f32_16x16x32_bf16(a1h, b1l_, acc[1][1], 0, 0, 0);
      acc[1][1] = __builtin_amdgcn_mfma_f32_16x16x32_bf16(a1l, b1h_, acc[1][1], 0, 0, 0);
    }
    float bb1[2] = {b1[col0], b1[col0 + 16]};
    #pragma unroll
    for (int rt = 0; rt < 2; rt++)
      #pragma unroll
      for (int ct = 0; ct < 2; ct++) {
        int colk = col0 + ct * 16;
        #pragma unroll
        for (int reg = 0; reg < 4; reg++) {
          int row = rt * 16 + quad * 4 + reg;
          float v = ssp_f(acc[rt][ct][reg] + bb1[ct]);
          unsigned short hb = bf16_rne(v);
          tH[row][colk] = (short)hb;
          tL[row][colk] = (short)bf16_rne(v - bf16_to_f(hb));
        }
      }
  }
  __syncthreads();

  // ---- GEMM2: out = t@W2 + b2 (+ residual) ----
  {
    f32x4 acc[2][2] = {};
    #pragma unroll
    for (int kb = 0; kb < 4; kb++) {
      int ko = kb * 32 + quad * 8;
      short8_t a0h = *(const short8_t*)&tH[ln][ko];
      short8_t a0l = *(const short8_t*)&tL[ln][ko];
      short8_t a1h = *(const short8_t*)&tH[16 + ln][ko];
      short8_t a1l = *(const short8_t*)&tL[16 + ln][ko];
      const short* pb = pw2 + ((kb * 8 + wid * 2) * 64 + lane) * 8;
      short8_t b0h = *(const short8_t*)pb;
      short8_t b0l = *(const short8_t*)(pb + 16384);
      short8_t b1h_ = *(const short8_t*)(pb + 512);
      short8_t b1l_ = *(const short8_t*)(pb + 16384 + 512);
      acc[0][0] = __builtin_amdgcn_mfma_f32_16x16x32_bf16(a0h, b0h, acc[0][0], 0, 0, 0);
      acc[0][0] = __builtin_amdgcn_mfma_f32_16x16x32_bf16(a0h, b0l, acc[0][0], 0, 0, 0);
      acc[0][0] = __builtin_amdgcn_mfma_f32_16x16x32_bf16(a0l, b0h, acc[0][0], 0, 0, 0);
      acc[0][1] = __builtin_amdgcn_mfma_f32_16x16x32_bf16(a0h, b1h_, acc[0][1], 0, 0, 0);
      acc[0][1] = __builtin_amdgcn_mfma_f32_16x16x32_bf16(a0h, b1l_, acc[0][1], 0, 0, 0);
      acc[0][1] = __builtin_amdgcn_mfma_f32_16x16x32_bf16(a0l, b1h_, acc[0][1], 0, 0, 0);
      acc[1][0] = __builtin_amdgcn_mfma_f32_16x16x32_bf16(a1h, b0h, acc[1][0], 0, 0, 0);
      acc[1][0] = __builtin_amdgcn_mfma_f32_16x16x32_bf16(a1h, b0l, acc[1][0], 0, 0, 0);
      acc[1][0] = __builtin_amdgcn_mfma_f32_16x16x32_bf16(a1l, b0h, acc[1][0], 0, 0, 0);
      acc[1][1] = __builtin_amdgcn_mfma_f32_16x16x32_bf16(a1h, b1h_, acc[1][1], 0, 0, 0);
      acc[1][1] = __builtin_amdgcn_mfma_f32_16x16x32_bf16(a1h, b1l_, acc[1][1], 0, 0, 0);
      acc[1][1] = __builtin_amdgcn_mfma_f32_16x16x32_bf16(a1l, b1h_, acc[1][1], 0, 0, 0);
    }
    float bb2[2] = {b2[col0], b2[col0 + 16]};
    #pragma unroll
    for (int rt = 0; rt < 2; rt++)
      #pragma unroll
      for (int ct = 0; ct < 2; ct++) {
        int col = col0 + ct * 16;
        #pragma unroll
        for (int reg = 0; reg < 4; reg++) {
          int row = rt * 16 + quad * 4 + reg;
          size_t gi = (size_t)(rb + row) * H + col;
          float v = acc[rt][ct][reg] + bb2[ct];
          if (residual) v += hio[gi];
          hio[gi] = v;
        }
      }
  }
}

// per-mol pooling (256 contiguous atoms) + head MLP
__global__ __launch_bounds__(256) void k_pool_head(const float* __restrict__ h2,
                                                   const float* __restrict__ hw1,
                                                   const float* __restrict__ hb1,
                                                   const float* __restrict__ hw2,
                                                   const float* __restrict__ hb2,
                                                   float* __restrict__ outp) {
  int m = blockIdx.x;
  int c = threadIdx.x & 127;
  int half = threadIdx.x >> 7;
  __shared__ float mol2[2][128];
  __shared__ float q[64];
  const float* base = h2 + (size_t)m * 256 * H;
  float s = 0.f;
  for (int a = half; a < 256; a += 2) s += base[(size_t)a * H + c];
  mol2[half][c] = s;
  __syncthreads();
  if (threadIdx.x < 64) {
    int j = threadIdx.x;
    float qq = hb1[j];
    #pragma unroll 8
    for (int cc = 0; cc < H; cc++) qq += (mol2[0][cc] + mol2[1][cc]) * hw1[cc * 64 + j];
    q[j] = ssp_f(qq);
  }
  __syncthreads();
  if (threadIdx.x == 0) {
    float o = hb2[0];
    for (int j = 0; j < 64; j++) o += q[j] * hw2[j];
    outp[m] = o;
  }
}

extern "C" void kernel_launch(void* const* d_in, const int* in_sizes, int n_in,
                              void* d_out, int out_size, void* d_ws, size_t ws_size,
                              hipStream_t stream) {
  const int*   z       = (const int*)d_in[0];
  const float* pos     = (const float*)d_in[1];
  const int*   eidx    = (const int*)d_in[2];
  const float* emb     = (const float*)d_in[5];
  const float* mlp_w1  = (const float*)d_in[6];
  const float* mlp_b1  = (const float*)d_in[7];
  const float* mlp_w2  = (const float*)d_in[8];
  const float* mlp_b2  = (const float*)d_in[9];
  const float* cf_w1   = (const float*)d_in[10];
  const float* cf_w2   = (const float*)d_in[11];
  const float* cf_b2   = (const float*)d_in[12];
  const float* int_w   = (const float*)d_in[13];
  const float* int_b   = (const float*)d_in[14];
  const float* out_w1  = (const float*)d_in[15];
  const float* out_b1  = (const float*)d_in[16];
  const float* out_w2  = (const float*)d_in[17];
  const float* out_b2  = (const float*)d_in[18];
  const float* head_w1 = (const float*)d_in[19];
  const float* head_b1 = (const float*)d_in[20];
  const float* head_w2 = (const float*)d_in[21];
  const float* head_b2 = (const float*)d_in[22];

  float* ws   = (float*)d_ws;
  float* T    = ws;                          // 786,432 floats
  float* h    = T + (size_t)NL * TP * H;     // 2,097,152
  float* agg  = h + (size_t)N_ATOMS * H;     // 2,097,152
  float* h2   = agg + (size_t)N_ATOMS * H;   // 2,097,152
  float* frac = h2 + (size_t)N_ATOMS * H;    // 524,288
  int*   pk   = (int*)(frac + NEDGE);        // 524,288 ints
  short* PW   = (short*)(pk + NEDGE);        // 14*32768 shorts

  k_embed<<<(N_ATOMS * H) / 256, 256, 0, stream>>>(z, emb, h);
  k_edge_prep<<<NEDGE / 256, 256, 0, stream>>>(pos, eidx, eidx + NEDGE, pk, frac);
  k_table<<<NL * (TP / 2), 256, 0, stream>>>(mlp_w1, mlp_b1, mlp_w2, mlp_b2, T);
  k_prep<<<(14 * 16384) / 256, 256, 0, stream>>>(cf_w2, int_w, out_w1, out_w2, PW);

  for (int l = 0; l < NL; l++) {
    k_conf<<<N_CONF, 256, 0, stream>>>(h, cf_w1 + (size_t)l * H * H,
                                       T + (size_t)l * TP * H, pk, frac, agg);
    k_node2_mfma<<<N_ATOMS / 32, 256, 0, stream>>>(
        agg, PW + (size_t)(2 * l) * 32768, cf_b2 + (size_t)l * H,
        PW + (size_t)(2 * l + 1) * 32768, int_b + (size_t)l * H, h, 1);
  }

  k_node2_mfma<<<N_ATOMS / 32, 256, 0, stream>>>(
      h, PW + (size_t)12 * 32768, out_b1, PW + (size_t)13 * 32768, out_b2, h2, 0);
  k_pool_head<<<N_MOL, 256, 0, stream>>>(h2, head_w1, head_b1, head_w2, head_b2,
                                         (float*)d_out);
}

// Round 4
// 379.587 us; speedup vs baseline: 2.2594x; 1.2679x over previous
//
#include <hip/hip_runtime.h>
#include <math.h>

#define N_ATOMS 16384
#define APC 64
#define N_CONF 256
#define N_MOL 64
#define DEG 32
#define NEDGE (N_ATOMS * DEG)
#define H 128
#define G 50
#define NL 6
#define TP0 1024         // fp32 source table points
#define TPB 4096         // bf16 nearest table points
#define CUTOFF 10.0f

typedef __attribute__((ext_vector_type(8))) short short8_t;
typedef __attribute__((ext_vector_type(4))) float f32x4;

__device__ __forceinline__ float ssp_f(float x) {
  return fmaxf(x, 0.f) + log1pf(expf(-fabsf(x))) - 0.69314718055994531f;
}
__device__ __forceinline__ unsigned short bf16_rne(float x) {
  unsigned u = __float_as_uint(x);
  unsigned r = u + 0x7FFF + ((u >> 16) & 1);
  return (unsigned short)(r >> 16);
}
__device__ __forceinline__ float bf16_to_f(unsigned short s) {
  return __uint_as_float(((unsigned)s) << 16);
}

// h[n][c] = emb[z[n]][c]
__global__ __launch_bounds__(256) void k_embed(const int* __restrict__ z,
                                               const float* __restrict__ emb,
                                               float* __restrict__ h) {
  int i = blockIdx.x * 256 + threadIdx.x;
  int n = i >> 7, c = i & 127;
  h[i] = emb[z[n] * H + c];
}

// per-edge: distance -> packed (nearest table index | src_local<<16)
__global__ __launch_bounds__(256) void k_edge_prep(const float* __restrict__ pos,
                                                   const int* __restrict__ esrc,
                                                   const int* __restrict__ etgt,
                                                   int* __restrict__ pk) {
  int e = blockIdx.x * 256 + threadIdx.x;
  int r = esrc[e], c = etgt[e];
  float dx = pos[r * 3 + 0] - pos[c * 3 + 0];
  float dy = pos[r * 3 + 1] - pos[c * 3 + 1];
  float dz = pos[r * 3 + 2] - pos[c * 3 + 2];
  float d = sqrtf(dx * dx + dy * dy + dz * dz);
  int i = (int)(d * ((float)(TPB - 1) / CUTOFF) + 0.5f);
  if (i > TPB - 1) i = TPB - 1;
  if (i < 0) i = 0;
  pk[e] = i | ((r & (APC - 1)) << 16);
}

// fp32 source table T[l][p][c] at TP0 points; 2 points per 256-thread block
__global__ __launch_bounds__(256) void k_table(const float* __restrict__ w1,
                                               const float* __restrict__ b1,
                                               const float* __restrict__ w2,
                                               const float* __restrict__ b2,
                                               float* __restrict__ T) {
  const int l = blockIdx.x >> 9;
  const int grp = threadIdx.x >> 7;
  const int c = threadIdx.x & 127;
  const int p = (blockIdx.x & 511) * 2 + grp;
  const float d = (float)p * (CUTOFF / (float)(TP0 - 1));
  __shared__ float g2[2][64];
  __shared__ float S2[2][128];
  const float gspace = CUTOFF / (float)(G - 1);
  const float coeff = -0.5f / (gspace * gspace);
  if (c < G) {
    float x = d - (float)c * gspace;
    g2[grp][c] = expf(coeff * x * x);
  }
  __syncthreads();
  const float* W1 = w1 + l * G * H;
  float s = b1[l * H + c];
  #pragma unroll 5
  for (int i = 0; i < G; i++) s += g2[grp][i] * W1[i * H + c];
  S2[grp][c] = ssp_f(s);
  __syncthreads();
  const float* W2 = w2 + l * H * H;
  float o = b2[l * H + c];
  #pragma unroll 8
  for (int j = 0; j < H; j++) o += S2[grp][j] * W2[j * H + c];
  float Cc = 0.5f * (cosf(d * (3.14159265358979f / CUTOFF)) + 1.f);
  T[((size_t)l * TP0 + p) * H + c] = o * Cc;
}

// upsample fp32 TP0 table -> bf16 TPB nearest table via lerp
__global__ __launch_bounds__(256) void k_up(const float* __restrict__ T,
                                            unsigned short* __restrict__ Tb) {
  int flat = blockIdx.x * 256 + threadIdx.x;   // < NL*TPB*H
  int l = flat >> 19;                          // TPB*H = 524288
  int rem = flat & 524287;
  int p4 = rem >> 7, c = rem & 127;
  float u = (float)p4 * ((float)(TP0 - 1) / (float)(TPB - 1));
  int i = (int)u;
  if (i > TP0 - 2) i = TP0 - 2;
  float f = u - (float)i;
  const float* Tl = T + ((size_t)l * TP0 + i) * H + c;
  float v = Tl[0] + f * (Tl[H] - Tl[0]);
  Tb[flat] = bf16_rne(v);
}

// Pre-swizzle weights into MFMA B-fragment order (bf16 hi/lo), 16B per thread.
// groups: 0..11 = (cf_w2,int_w) per layer; 12..17 = cf_w1[l]; 18 = out_w1; 19 = out_w2
__global__ __launch_bounds__(256) void k_prep(const float* __restrict__ cf_w1,
                                              const float* __restrict__ cf_w2,
                                              const float* __restrict__ int_w,
                                              const float* __restrict__ out_w1,
                                              const float* __restrict__ out_w2,
                                              short* __restrict__ PW) {
  int e = blockIdx.x * 256 + threadIdx.x;   // < 20*2048
  int g = e >> 11, t = e & 2047;
  int kb = t >> 9, rem = t & 511, nt = rem >> 6, lane = rem & 63;
  int quad = lane >> 4, ln = lane & 15;
  int kbase = kb * 32 + quad * 8;
  int n = nt * 16 + ln;
  const float* src;
  if (g < 12) {
    int l = g >> 1;
    src = (g & 1) ? (int_w + l * 16384) : (cf_w2 + l * 16384);
  } else if (g < 18) {
    src = cf_w1 + (g - 12) * 16384;
  } else {
    src = (g == 18) ? out_w1 : out_w2;
  }
  short hv[8], lv[8];
  #pragma unroll
  for (int j = 0; j < 8; j++) {
    float x = src[(kbase + j) * H + n];
    unsigned short hb = bf16_rne(x);
    hv[j] = (short)hb;
    lv[j] = (short)bf16_rne(x - bf16_to_f(hb));
  }
  size_t base = (size_t)g * 32768 + (size_t)t * 8;
  *(short8_t*)&PW[base] = *(short8_t*)hv;
  *(short8_t*)&PW[base + 16384] = *(short8_t*)lv;
}

// Per-block: 16 atoms of one conformer. xf tile (64x128 bf16) staged in LDS.
// agg[a][c] = sum_e Tb[idx_e][c] * xf[src_e][c]
__global__ __launch_bounds__(256) void k_conf(const unsigned short* __restrict__ xfb,
                                              const unsigned short* __restrict__ Tb,
                                              const int* __restrict__ pk,
                                              float* __restrict__ agg) {
  __shared__ unsigned short xs[64][132];
  __shared__ int pks[512];
  const int b = blockIdx.x;
  const int conf = b >> 2, sub = b & 3;
  const int tid = threadIdx.x;
  // stage xf tile (conformer's 64 atoms, bf16)
  {
    int r = tid >> 2, cp = (tid & 3) * 32;
    const unsigned short* src = xfb + ((size_t)conf * 64 + r) * H + cp;
    #pragma unroll
    for (int q = 0; q < 4; q++)
      *(short8_t*)&xs[r][cp + q * 8] = *(const short8_t*)(src + q * 8);
  }
  // stage this block's 512 edge records
  const int ebase = (conf * 64 + sub * 16) * DEG;
  pks[tid] = pk[ebase + tid];
  pks[tid + 256] = pk[ebase + 256 + tid];
  __syncthreads();
  const int gid = tid >> 5, ln = tid & 31;
  const int c0 = ln * 4;
  #pragma unroll
  for (int pass = 0; pass < 2; pass++) {
    int al = pass * 8 + gid;   // local atom 0..15
    float4 acc = {0.f, 0.f, 0.f, 0.f};
    #pragma unroll 8
    for (int e = 0; e < DEG; e++) {
      int m = pks[al * DEG + e];
      int idx = m & 0xFFFF, sl = m >> 16;
      uint2 tv = *(const uint2*)&Tb[(size_t)idx * H + c0];
      uint2 xv = *(const uint2*)&xs[sl][c0];
      float t0 = __uint_as_float(tv.x << 16);
      float t1 = __uint_as_float(tv.x & 0xFFFF0000u);
      float t2 = __uint_as_float(tv.y << 16);
      float t3 = __uint_as_float(tv.y & 0xFFFF0000u);
      float x0 = __uint_as_float(xv.x << 16);
      float x1 = __uint_as_float(xv.x & 0xFFFF0000u);
      float x2 = __uint_as_float(xv.y << 16);
      float x3 = __uint_as_float(xv.y & 0xFFFF0000u);
      acc.x += t0 * x0;
      acc.y += t1 * x1;
      acc.z += t2 * x2;
      acc.w += t3 * x3;
    }
    int atom = conf * 64 + sub * 16 + al;
    *(float4*)&agg[(size_t)atom * H + c0] = acc;
  }
}

#define MFMA(a, b, c) __builtin_amdgcn_mfma_f32_16x16x32_bf16((a), (b), (c), 0, 0, 0)

// Node MLP on matrix cores (16-row blocks, bf16x3 split), with optional fused
// xf GEMM (pw3): hio = (residual? hio:0) + ssp(A@W1+b1)@W2 + b2; xfb = bf16(hio@W3)
__global__ __launch_bounds__(256) void k_node2_mfma(
    const float* __restrict__ A, const short* __restrict__ pw1,
    const float* __restrict__ b1, const short* __restrict__ pw2,
    const float* __restrict__ b2, float* __restrict__ hio, int residual,
    const short* __restrict__ pw3, unsigned short* __restrict__ xfb) {
  __shared__ __align__(16) short sH[16][136];
  __shared__ __align__(16) short sL[16][136];
  const int tid = threadIdx.x;
  const int rb = blockIdx.x * 16;
  // stage + split A tile
  {
    int r = tid >> 4, cb = (tid & 15) * 8;
    const float* src = A + (size_t)(rb + r) * H + cb;
    float4 v0 = *(const float4*)src, v1 = *(const float4*)(src + 4);
    float vv[8] = {v0.x, v0.y, v0.z, v0.w, v1.x, v1.y, v1.z, v1.w};
    short hv[8], lv[8];
    #pragma unroll
    for (int u = 0; u < 8; u++) {
      unsigned short hb = bf16_rne(vv[u]);
      hv[u] = (short)hb;
      lv[u] = (short)bf16_rne(vv[u] - bf16_to_f(hb));
    }
    *(short8_t*)&sH[r][cb] = *(short8_t*)hv;
    *(short8_t*)&sL[r][cb] = *(short8_t*)lv;
  }
  __syncthreads();
  const int lane = tid & 63, wid = tid >> 6;
  const int quad = lane >> 4, ln = lane & 15;
  const int col0 = wid * 32 + ln;

  f32x4 acc0, acc1;
  // ---- GEMM1 ----
  acc0 = (f32x4){0.f, 0.f, 0.f, 0.f};
  acc1 = (f32x4){0.f, 0.f, 0.f, 0.f};
  #pragma unroll
  for (int kb = 0; kb < 4; kb++) {
    int ko = kb * 32 + quad * 8;
    short8_t ah = *(const short8_t*)&sH[ln][ko];
    short8_t al = *(const short8_t*)&sL[ln][ko];
    const short* pb = pw1 + ((size_t)(kb * 8 + wid * 2) * 64 + lane) * 8;
    short8_t b0h = *(const short8_t*)pb;
    short8_t b0l = *(const short8_t*)(pb + 16384);
    short8_t c1h = *(const short8_t*)(pb + 512);
    short8_t c1l = *(const short8_t*)(pb + 16384 + 512);
    acc0 = MFMA(ah, b0h, acc0); acc0 = MFMA(ah, b0l, acc0); acc0 = MFMA(al, b0h, acc0);
    acc1 = MFMA(ah, c1h, acc1); acc1 = MFMA(ah, c1l, acc1); acc1 = MFMA(al, c1h, acc1);
  }
  __syncthreads();
  {
    float ba = b1[col0], bb = b1[col0 + 16];
    #pragma unroll
    for (int reg = 0; reg < 4; reg++) {
      int row = quad * 4 + reg;
      float v0 = ssp_f(acc0[reg] + ba);
      float v1 = ssp_f(acc1[reg] + bb);
      unsigned short h0 = bf16_rne(v0), h1 = bf16_rne(v1);
      sH[row][col0] = (short)h0;
      sL[row][col0] = (short)bf16_rne(v0 - bf16_to_f(h0));
      sH[row][col0 + 16] = (short)h1;
      sL[row][col0 + 16] = (short)bf16_rne(v1 - bf16_to_f(h1));
    }
  }
  __syncthreads();
  // ---- GEMM2 ----
  acc0 = (f32x4){0.f, 0.f, 0.f, 0.f};
  acc1 = (f32x4){0.f, 0.f, 0.f, 0.f};
  #pragma unroll
  for (int kb = 0; kb < 4; kb++) {
    int ko = kb * 32 + quad * 8;
    short8_t ah = *(const short8_t*)&sH[ln][ko];
    short8_t al = *(const short8_t*)&sL[ln][ko];
    const short* pb = pw2 + ((size_t)(kb * 8 + wid * 2) * 64 + lane) * 8;
    short8_t b0h = *(const short8_t*)pb;
    short8_t b0l = *(const short8_t*)(pb + 16384);
    short8_t c1h = *(const short8_t*)(pb + 512);
    short8_t c1l = *(const short8_t*)(pb + 16384 + 512);
    acc0 = MFMA(ah, b0h, acc0); acc0 = MFMA(ah, b0l, acc0); acc0 = MFMA(al, b0h, acc0);
    acc1 = MFMA(ah, c1h, acc1); acc1 = MFMA(ah, c1l, acc1); acc1 = MFMA(al, c1h, acc1);
  }
  __syncthreads();
  {
    float ba = b2[col0], bb = b2[col0 + 16];
    #pragma unroll
    for (int reg = 0; reg < 4; reg++) {
      int row = quad * 4 + reg;
      size_t g0 = (size_t)(rb + row) * H + col0;
      float v0 = acc0[reg] + ba;
      float v1 = acc1[reg] + bb;
      if (residual) { v0 += hio[g0]; v1 += hio[g0 + 16]; }
      hio[g0] = v0;
      hio[g0 + 16] = v1;
      if (pw3) {
        unsigned short h0 = bf16_rne(v0), h1 = bf16_rne(v1);
        sH[row][col0] = (short)h0;
        sL[row][col0] = (short)bf16_rne(v0 - bf16_to_f(h0));
        sH[row][col0 + 16] = (short)h1;
        sL[row][col0 + 16] = (short)bf16_rne(v1 - bf16_to_f(h1));
      }
    }
  }
  if (pw3) {
    __syncthreads();
    acc0 = (f32x4){0.f, 0.f, 0.f, 0.f};
    acc1 = (f32x4){0.f, 0.f, 0.f, 0.f};
    #pragma unroll
    for (int kb = 0; kb < 4; kb++) {
      int ko = kb * 32 + quad * 8;
      short8_t ah = *(const short8_t*)&sH[ln][ko];
      short8_t al = *(const short8_t*)&sL[ln][ko];
      const short* pb = pw3 + ((size_t)(kb * 8 + wid * 2) * 64 + lane) * 8;
      short8_t b0h = *(const short8_t*)pb;
      short8_t b0l = *(const short8_t*)(pb + 16384);
      short8_t c1h = *(const short8_t*)(pb + 512);
      short8_t c1l = *(const short8_t*)(pb + 16384 + 512);
      acc0 = MFMA(ah, b0h, acc0); acc0 = MFMA(ah, b0l, acc0); acc0 = MFMA(al, b0h, acc0);
      acc1 = MFMA(ah, c1h, acc1); acc1 = MFMA(ah, c1l, acc1); acc1 = MFMA(al, c1h, acc1);
    }
    #pragma unroll
    for (int reg = 0; reg < 4; reg++) {
      int row = quad * 4 + reg;
      size_t g0 = (size_t)(rb + row) * H + col0;
      xfb[g0] = bf16_rne(acc0[reg]);
      xfb[g0 + 16] = bf16_rne(acc1[reg]);
    }
  }
}

// first xf: xfb = bf16(h @ cf_w1[0])   (no bias)
__global__ __launch_bounds__(256) void k_xf(const float* __restrict__ A,
                                            const short* __restrict__ pw,
                                            unsigned short* __restrict__ xfb) {
  __shared__ __align__(16) short sH[16][136];
  __shared__ __align__(16) short sL[16][136];
  const int tid = threadIdx.x;
  const int rb = blockIdx.x * 16;
  {
    int r = tid >> 4, cb = (tid & 15) * 8;
    const float* src = A + (size_t)(rb + r) * H + cb;
    float4 v0 = *(const float4*)src, v1 = *(const float4*)(src + 4);
    float vv[8] = {v0.x, v0.y, v0.z, v0.w, v1.x, v1.y, v1.z, v1.w};
    short hv[8], lv[8];
    #pragma unroll
    for (int u = 0; u < 8; u++) {
      unsigned short hb = bf16_rne(vv[u]);
      hv[u] = (short)hb;
      lv[u] = (short)bf16_rne(vv[u] - bf16_to_f(hb));
    }
    *(short8_t*)&sH[r][cb] = *(short8_t*)hv;
    *(short8_t*)&sL[r][cb] = *(short8_t*)lv;
  }
  __syncthreads();
  const int lane = tid & 63, wid = tid >> 6;
  const int quad = lane >> 4, ln = lane & 15;
  const int col0 = wid * 32 + ln;
  f32x4 acc0 = (f32x4){0.f, 0.f, 0.f, 0.f};
  f32x4 acc1 = (f32x4){0.f, 0.f, 0.f, 0.f};
  #pragma unroll
  for (int kb = 0; kb < 4; kb++) {
    int ko = kb * 32 + quad * 8;
    short8_t ah = *(const short8_t*)&sH[ln][ko];
    short8_t al = *(const short8_t*)&sL[ln][ko];
    const short* pb = pw + ((size_t)(kb * 8 + wid * 2) * 64 + lane) * 8;
    short8_t b0h = *(const short8_t*)pb;
    short8_t b0l = *(const short8_t*)(pb + 16384);
    short8_t c1h = *(const short8_t*)(pb + 512);
    short8_t c1l = *(const short8_t*)(pb + 16384 + 512);
    acc0 = MFMA(ah, b0h, acc0); acc0 = MFMA(ah, b0l, acc0); acc0 = MFMA(al, b0h, acc0);
    acc1 = MFMA(ah, c1h, acc1); acc1 = MFMA(ah, c1l, acc1); acc1 = MFMA(al, c1h, acc1);
  }
  #pragma unroll
  for (int reg = 0; reg < 4; reg++) {
    int row = quad * 4 + reg;
    size_t g0 = (size_t)(rb + row) * H + col0;
    xfb[g0] = bf16_rne(acc0[reg]);
    xfb[g0 + 16] = bf16_rne(acc1[reg]);
  }
}

// per-mol pooling (256 contiguous atoms) + head MLP
__global__ __launch_bounds__(256) void k_pool_head(const float* __restrict__ h2,
                                                   const float* __restrict__ hw1,
                                                   const float* __restrict__ hb1,
                                                   const float* __restrict__ hw2,
                                                   const float* __restrict__ hb2,
                                                   float* __restrict__ outp) {
  int m = blockIdx.x;
  int c = threadIdx.x & 127;
  int half = threadIdx.x >> 7;
  __shared__ float mol2[2][128];
  __shared__ float q[64];
  const float* base = h2 + (size_t)m * 256 * H;
  float s = 0.f;
  for (int a = half; a < 256; a += 2) s += base[(size_t)a * H + c];
  mol2[half][c] = s;
  __syncthreads();
  if (threadIdx.x < 64) {
    int j = threadIdx.x;
    float qq = hb1[j];
    #pragma unroll 8
    for (int cc = 0; cc < H; cc++) qq += (mol2[0][cc] + mol2[1][cc]) * hw1[cc * 64 + j];
    q[j] = ssp_f(qq);
  }
  __syncthreads();
  if (threadIdx.x == 0) {
    float o = hb2[0];
    for (int j = 0; j < 64; j++) o += q[j] * hw2[j];
    outp[m] = o;
  }
}

extern "C" void kernel_launch(void* const* d_in, const int* in_sizes, int n_in,
                              void* d_out, int out_size, void* d_ws, size_t ws_size,
                              hipStream_t stream) {
  const int*   z       = (const int*)d_in[0];
  const float* pos     = (const float*)d_in[1];
  const int*   eidx    = (const int*)d_in[2];
  const float* emb     = (const float*)d_in[5];
  const float* mlp_w1  = (const float*)d_in[6];
  const float* mlp_b1  = (const float*)d_in[7];
  const float* mlp_w2  = (const float*)d_in[8];
  const float* mlp_b2  = (const float*)d_in[9];
  const float* cf_w1   = (const float*)d_in[10];
  const float* cf_w2   = (const float*)d_in[11];
  const float* cf_b2   = (const float*)d_in[12];
  const float* int_w   = (const float*)d_in[13];
  const float* int_b   = (const float*)d_in[14];
  const float* out_w1  = (const float*)d_in[15];
  const float* out_b1  = (const float*)d_in[16];
  const float* out_w2  = (const float*)d_in[17];
  const float* out_b2  = (const float*)d_in[18];
  const float* head_w1 = (const float*)d_in[19];
  const float* head_b1 = (const float*)d_in[20];
  const float* head_w2 = (const float*)d_in[21];
  const float* head_b2 = (const float*)d_in[22];

  float* ws = (float*)d_ws;
  float*          T   = ws;                                   // 786,432 f
  unsigned short* Tb  = (unsigned short*)(T + 786432);        // 3,145,728 us
  float*          h   = (float*)(Tb + 3145728);               // 2,097,152 f
  float*          agg = h + 2097152;                          // 2,097,152 f
  float*          h2  = agg + 2097152;                        // 2,097,152 f
  unsigned short* xfb = (unsigned short*)(h2 + 2097152);      // 2,097,152 us
  int*            pk  = (int*)(xfb + 2097152);                // 524,288 i
  short*          PW  = (short*)(pk + 524288);                // 20*32768 s

  k_embed<<<(N_ATOMS * H) / 256, 256, 0, stream>>>(z, emb, h);
  k_edge_prep<<<NEDGE / 256, 256, 0, stream>>>(pos, eidx, eidx + NEDGE, pk);
  k_table<<<NL * (TP0 / 2), 256, 0, stream>>>(mlp_w1, mlp_b1, mlp_w2, mlp_b2, T);
  k_prep<<<(20 * 2048) / 256, 256, 0, stream>>>(cf_w1, cf_w2, int_w, out_w1, out_w2, PW);
  k_up<<<(NL * TPB * H) / 256, 256, 0, stream>>>(T, Tb);
  k_xf<<<N_ATOMS / 16, 256, 0, stream>>>(h, PW + (size_t)12 * 32768, xfb);

  for (int l = 0; l < NL; l++) {
    k_conf<<<N_CONF * 4, 256, 0, stream>>>(xfb, Tb + (size_t)l * TPB * H, pk, agg);
    const short* pw3 = (l < NL - 1) ? (PW + (size_t)(13 + l) * 32768) : nullptr;
    k_node2_mfma<<<N_ATOMS / 16, 256, 0, stream>>>(
        agg, PW + (size_t)(2 * l) * 32768, cf_b2 + (size_t)l * H,
        PW + (size_t)(2 * l + 1) * 32768, int_b + (size_t)l * H, h, 1, pw3, xfb);
  }

  k_node2_mfma<<<N_ATOMS / 16, 256, 0, stream>>>(
      h, PW + (size_t)18 * 32768, out_b1, PW + (size_t)19 * 32768, out_b2, h2, 0,
      nullptr, xfb);
  k_pool_head<<<N_MOL, 256, 0, stream>>>(h2, head_w1, head_b1, head_w2, head_b2,
                                         (float*)d_out);
}

// Round 5
// 345.143 us; speedup vs baseline: 2.4849x; 1.0998x over previous
//
#include <hip/hip_runtime.h>
#include <math.h>

#define N_ATOMS 16384
#define APC 64
#define N_CONF 256
#define N_MOL 64
#define DEG 32
#define NEDGE (N_ATOMS * DEG)
#define H 128
#define G 50
#define NL 6
#define TP0 1024         // fp32 source table points
#define TPB 4096         // bf16 nearest table points
#define CUTOFF 10.0f

typedef __attribute__((ext_vector_type(8))) short short8_t;
typedef __attribute__((ext_vector_type(4))) float f32x4;

__device__ __forceinline__ float ssp_f(float x) {
  return fmaxf(x, 0.f) + log1pf(expf(-fabsf(x))) - 0.69314718055994531f;
}
__device__ __forceinline__ unsigned short bf16_rne(float x) {
  unsigned u = __float_as_uint(x);
  unsigned r = u + 0x7FFF + ((u >> 16) & 1);
  return (unsigned short)(r >> 16);
}
__device__ __forceinline__ float bf16_to_f(unsigned short s) {
  return __uint_as_float(((unsigned)s) << 16);
}

// per-edge: distance -> packed (nearest table index | src_local<<16)
__global__ __launch_bounds__(256) void k_edge_prep(const float* __restrict__ pos,
                                                   const int* __restrict__ esrc,
                                                   const int* __restrict__ etgt,
                                                   int* __restrict__ pk) {
  int e = blockIdx.x * 256 + threadIdx.x;
  int r = esrc[e], c = etgt[e];
  float dx = pos[r * 3 + 0] - pos[c * 3 + 0];
  float dy = pos[r * 3 + 1] - pos[c * 3 + 1];
  float dz = pos[r * 3 + 2] - pos[c * 3 + 2];
  float d = sqrtf(dx * dx + dy * dy + dz * dz);
  int i = (int)(d * ((float)(TPB - 1) / CUTOFF) + 0.5f);
  if (i > TPB - 1) i = TPB - 1;
  if (i < 0) i = 0;
  pk[e] = i | ((r & (APC - 1)) << 16);
}

// fp32 source table T[l][p][c] at TP0 points; 2 points per 256-thread block
__global__ __launch_bounds__(256) void k_table(const float* __restrict__ w1,
                                               const float* __restrict__ b1,
                                               const float* __restrict__ w2,
                                               const float* __restrict__ b2,
                                               float* __restrict__ T) {
  const int l = blockIdx.x >> 9;
  const int grp = threadIdx.x >> 7;
  const int c = threadIdx.x & 127;
  const int p = (blockIdx.x & 511) * 2 + grp;
  const float d = (float)p * (CUTOFF / (float)(TP0 - 1));
  __shared__ float g2[2][64];
  __shared__ float S2[2][128];
  const float gspace = CUTOFF / (float)(G - 1);
  const float coeff = -0.5f / (gspace * gspace);
  if (c < G) {
    float x = d - (float)c * gspace;
    g2[grp][c] = expf(coeff * x * x);
  }
  __syncthreads();
  const float* W1 = w1 + l * G * H;
  float s = b1[l * H + c];
  #pragma unroll 5
  for (int i = 0; i < G; i++) s += g2[grp][i] * W1[i * H + c];
  S2[grp][c] = ssp_f(s);
  __syncthreads();
  const float* W2 = w2 + l * H * H;
  float o = b2[l * H + c];
  #pragma unroll 8
  for (int j = 0; j < H; j++) o += S2[grp][j] * W2[j * H + c];
  float Cc = 0.5f * (cosf(d * (3.14159265358979f / CUTOFF)) + 1.f);
  T[((size_t)l * TP0 + p) * H + c] = o * Cc;
}

// upsample fp32 TP0 table -> bf16 TPB nearest table via lerp
__global__ __launch_bounds__(256) void k_up(const float* __restrict__ T,
                                            unsigned short* __restrict__ Tb) {
  int flat = blockIdx.x * 256 + threadIdx.x;   // < NL*TPB*H
  int l = flat >> 19;
  int rem = flat & 524287;
  int p4 = rem >> 7, c = rem & 127;
  float u = (float)p4 * ((float)(TP0 - 1) / (float)(TPB - 1));
  int i = (int)u;
  if (i > TP0 - 2) i = TP0 - 2;
  float f = u - (float)i;
  const float* Tl = T + ((size_t)l * TP0 + i) * H + c;
  float v = Tl[0] + f * (Tl[H] - Tl[0]);
  Tb[flat] = bf16_rne(v);
}

// Pre-swizzle weights into MFMA B-fragment order (bf16 hi/lo), 16B per thread.
// groups: 0..11 = (cf_w2,int_w) per layer; 12..17 = cf_w1[l]; 18 = out_w1; 19 = out_w2
__global__ __launch_bounds__(256) void k_prep(const float* __restrict__ cf_w1,
                                              const float* __restrict__ cf_w2,
                                              const float* __restrict__ int_w,
                                              const float* __restrict__ out_w1,
                                              const float* __restrict__ out_w2,
                                              short* __restrict__ PW) {
  int e = blockIdx.x * 256 + threadIdx.x;   // < 20*2048
  int g = e >> 11, t = e & 2047;
  int kb = t >> 9, rem = t & 511, nt = rem >> 6, lane = rem & 63;
  int quad = lane >> 4, ln = lane & 15;
  int kbase = kb * 32 + quad * 8;
  int n = nt * 16 + ln;
  const float* src;
  if (g < 12) {
    int l = g >> 1;
    src = (g & 1) ? (int_w + l * 16384) : (cf_w2 + l * 16384);
  } else if (g < 18) {
    src = cf_w1 + (g - 12) * 16384;
  } else {
    src = (g == 18) ? out_w1 : out_w2;
  }
  short hv[8], lv[8];
  #pragma unroll
  for (int j = 0; j < 8; j++) {
    float x = src[(kbase + j) * H + n];
    unsigned short hb = bf16_rne(x);
    hv[j] = (short)hb;
    lv[j] = (short)bf16_rne(x - bf16_to_f(hb));
  }
  size_t base = (size_t)g * 32768 + (size_t)t * 8;
  *(short8_t*)&PW[base] = *(short8_t*)hv;
  *(short8_t*)&PW[base + 16384] = *(short8_t*)lv;
}

#define MFMA(a, b, c) __builtin_amdgcn_mfma_f32_16x16x32_bf16((a), (b), (c), 0, 0, 0)

// one 16-row x2-coltile x3-split GEMM sweep: acc += A(sH,sL) @ B(pw)
__device__ __forceinline__ void gemm_tile(const short (*sH)[136], const short (*sL)[136],
                                          const short* __restrict__ pw,
                                          int ln, int quad, int wid,
                                          f32x4& acc0, f32x4& acc1) {
  #pragma unroll
  for (int kb = 0; kb < 4; kb++) {
    int ko = kb * 32 + quad * 8;
    short8_t ah = *(const short8_t*)&sH[ln][ko];
    short8_t al = *(const short8_t*)&sL[ln][ko];
    const short* pb = pw + ((size_t)(kb * 8 + wid * 2) * 64 + (quad * 16 + ln)) * 8;
    short8_t b0h = *(const short8_t*)pb;
    short8_t b0l = *(const short8_t*)(pb + 16384);
    short8_t c1h = *(const short8_t*)(pb + 512);
    short8_t c1l = *(const short8_t*)(pb + 16384 + 512);
    acc0 = MFMA(ah, b0h, acc0); acc0 = MFMA(ah, b0l, acc0); acc0 = MFMA(al, b0h, acc0);
    acc1 = MFMA(ah, c1h, acc1); acc1 = MFMA(ah, c1l, acc1); acc1 = MFMA(al, c1h, acc1);
  }
}

// Fused layer: edge aggregation (table * gathered xf) -> node MLP (3 MFMA GEMMs)
// block = 16 atoms of one conformer; grid = N_ATOMS/16
__global__ __launch_bounds__(256) void k_layer(
    const unsigned short* __restrict__ xf_in, const unsigned short* __restrict__ Tb,
    const int* __restrict__ pk, const short* __restrict__ pw1,
    const float* __restrict__ b1, const short* __restrict__ pw2,
    const float* __restrict__ b2, float* __restrict__ h,
    const short* __restrict__ pw3, unsigned short* __restrict__ xf_out) {
  __shared__ unsigned short xs[64][136];
  __shared__ int pks[512];
  __shared__ __align__(16) short sH[16][136];
  __shared__ __align__(16) short sL[16][136];
  const int tid = threadIdx.x;
  const int conf = blockIdx.x >> 2;
  const int rb = blockIdx.x * 16;          // global atom row base
  // stage xf tile of this conformer (64 x 128 bf16)
  {
    int r = tid >> 2, cp = (tid & 3) * 32;
    const unsigned short* src = xf_in + ((size_t)conf * 64 + r) * H + cp;
    #pragma unroll
    for (int q = 0; q < 4; q++)
      *(short8_t*)&xs[r][cp + q * 8] = *(const short8_t*)(src + q * 8);
  }
  // stage 512 edge records of this block's 16 atoms
  pks[tid] = pk[rb * DEG + tid];
  pks[tid + 256] = pk[rb * DEG + 256 + tid];
  __syncthreads();

  const int lane = tid & 63, wid = tid >> 6;
  const int eg = lane >> 4;            // edge subgroup 0..3
  const int chi = lane & 15;           // channel group (8 ch)
  const int ch0 = chi * 8;
  // phase 1: aggregate; wave w handles atoms w*4 .. w*4+3
  #pragma unroll
  for (int aa = 0; aa < 4; aa++) {
    int al = wid * 4 + aa;             // local atom 0..15
    float acc[8] = {};
    #pragma unroll
    for (int it = 0; it < 8; it++) {
      int m = pks[al * DEG + it * 4 + eg];
      int idx = m & 0xFFFF, sl = m >> 16;
      uint4 tv = *(const uint4*)&Tb[(size_t)idx * H + ch0];
      uint4 xv = *(const uint4*)&xs[sl][ch0];
      unsigned tw[4] = {tv.x, tv.y, tv.z, tv.w};
      unsigned xw[4] = {xv.x, xv.y, xv.z, xv.w};
      #pragma unroll
      for (int p = 0; p < 4; p++) {
        acc[2 * p]     += __uint_as_float(tw[p] << 16) * __uint_as_float(xw[p] << 16);
        acc[2 * p + 1] += __uint_as_float(tw[p] & 0xFFFF0000u) *
                          __uint_as_float(xw[p] & 0xFFFF0000u);
      }
    }
    #pragma unroll
    for (int j = 0; j < 8; j++) {
      acc[j] += __shfl_xor(acc[j], 16);
      acc[j] += __shfl_xor(acc[j], 32);
    }
    if (eg == 0) {
      short hv[8], lv[8];
      #pragma unroll
      for (int j = 0; j < 8; j++) {
        unsigned short hb = bf16_rne(acc[j]);
        hv[j] = (short)hb;
        lv[j] = (short)bf16_rne(acc[j] - bf16_to_f(hb));
      }
      *(short8_t*)&sH[al][ch0] = *(short8_t*)hv;
      *(short8_t*)&sL[al][ch0] = *(short8_t*)lv;
    }
  }
  __syncthreads();

  const int quad = lane >> 4, ln = lane & 15;
  const int col0 = wid * 32 + ln;
  f32x4 acc0, acc1;
  // ---- GEMM1: t = ssp(agg@cf_w2 + b1) ----
  acc0 = (f32x4){0.f, 0.f, 0.f, 0.f};
  acc1 = (f32x4){0.f, 0.f, 0.f, 0.f};
  gemm_tile(sH, sL, pw1, ln, quad, wid, acc0, acc1);
  __syncthreads();
  {
    float ba = b1[col0], bb = b1[col0 + 16];
    #pragma unroll
    for (int reg = 0; reg < 4; reg++) {
      int row = quad * 4 + reg;
      float v0 = ssp_f(acc0[reg] + ba);
      float v1 = ssp_f(acc1[reg] + bb);
      unsigned short h0 = bf16_rne(v0), h1 = bf16_rne(v1);
      sH[row][col0] = (short)h0;
      sL[row][col0] = (short)bf16_rne(v0 - bf16_to_f(h0));
      sH[row][col0 + 16] = (short)h1;
      sL[row][col0 + 16] = (short)bf16_rne(v1 - bf16_to_f(h1));
    }
  }
  __syncthreads();
  // ---- GEMM2: h += t@int_w + b2 ----
  acc0 = (f32x4){0.f, 0.f, 0.f, 0.f};
  acc1 = (f32x4){0.f, 0.f, 0.f, 0.f};
  gemm_tile(sH, sL, pw2, ln, quad, wid, acc0, acc1);
  __syncthreads();
  {
    float ba = b2[col0], bb = b2[col0 + 16];
    #pragma unroll
    for (int reg = 0; reg < 4; reg++) {
      int row = quad * 4 + reg;
      size_t g0 = (size_t)(rb + row) * H + col0;
      float v0 = acc0[reg] + ba + h[g0];
      float v1 = acc1[reg] + bb + h[g0 + 16];
      h[g0] = v0;
      h[g0 + 16] = v1;
      if (pw3) {
        unsigned short h0 = bf16_rne(v0), h1 = bf16_rne(v1);
        sH[row][col0] = (short)h0;
        sL[row][col0] = (short)bf16_rne(v0 - bf16_to_f(h0));
        sH[row][col0 + 16] = (short)h1;
        sL[row][col0 + 16] = (short)bf16_rne(v1 - bf16_to_f(h1));
      }
    }
  }
  if (pw3) {
    __syncthreads();
    // ---- GEMM3: xf_out = bf16(h_new @ cf_w1[l+1]) ----
    acc0 = (f32x4){0.f, 0.f, 0.f, 0.f};
    acc1 = (f32x4){0.f, 0.f, 0.f, 0.f};
    gemm_tile(sH, sL, pw3, ln, quad, wid, acc0, acc1);
    #pragma unroll
    for (int reg = 0; reg < 4; reg++) {
      int row = quad * 4 + reg;
      size_t g0 = (size_t)(rb + row) * H + col0;
      xf_out[g0] = bf16_rne(acc0[reg]);
      xf_out[g0 + 16] = bf16_rne(acc1[reg]);
    }
  }
}

// init: h = emb[z]; xf0 = bf16(h @ cf_w1[0])
__global__ __launch_bounds__(256) void k_init(const int* __restrict__ z,
                                              const float* __restrict__ emb,
                                              const short* __restrict__ pw,
                                              float* __restrict__ h,
                                              unsigned short* __restrict__ xfb) {
  __shared__ __align__(16) short sH[16][136];
  __shared__ __align__(16) short sL[16][136];
  const int tid = threadIdx.x;
  const int rb = blockIdx.x * 16;
  {
    int r = tid >> 4, cb = (tid & 15) * 8;
    const float* src = emb + (size_t)z[rb + r] * H + cb;
    float4 v0 = *(const float4*)src, v1 = *(const float4*)(src + 4);
    float* dst = h + (size_t)(rb + r) * H + cb;
    *(float4*)dst = v0;
    *(float4*)(dst + 4) = v1;
    float vv[8] = {v0.x, v0.y, v0.z, v0.w, v1.x, v1.y, v1.z, v1.w};
    short hv[8], lv[8];
    #pragma unroll
    for (int u = 0; u < 8; u++) {
      unsigned short hb = bf16_rne(vv[u]);
      hv[u] = (short)hb;
      lv[u] = (short)bf16_rne(vv[u] - bf16_to_f(hb));
    }
    *(short8_t*)&sH[r][cb] = *(short8_t*)hv;
    *(short8_t*)&sL[r][cb] = *(short8_t*)lv;
  }
  __syncthreads();
  const int lane = tid & 63, wid = tid >> 6;
  const int quad = lane >> 4, ln = lane & 15;
  const int col0 = wid * 32 + ln;
  f32x4 acc0 = (f32x4){0.f, 0.f, 0.f, 0.f};
  f32x4 acc1 = (f32x4){0.f, 0.f, 0.f, 0.f};
  gemm_tile(sH, sL, pw, ln, quad, wid, acc0, acc1);
  #pragma unroll
  for (int reg = 0; reg < 4; reg++) {
    int row = quad * 4 + reg;
    size_t g0 = (size_t)(rb + row) * H + col0;
    xfb[g0] = bf16_rne(acc0[reg]);
    xfb[g0 + 16] = bf16_rne(acc1[reg]);
  }
}

// readout: h2 = ssp(h@out_w1+b1)@out_w2 + b2
__global__ __launch_bounds__(256) void k_readout(
    const float* __restrict__ A, const short* __restrict__ pw1,
    const float* __restrict__ b1, const short* __restrict__ pw2,
    const float* __restrict__ b2, float* __restrict__ out) {
  __shared__ __align__(16) short sH[16][136];
  __shared__ __align__(16) short sL[16][136];
  const int tid = threadIdx.x;
  const int rb = blockIdx.x * 16;
  {
    int r = tid >> 4, cb = (tid & 15) * 8;
    const float* src = A + (size_t)(rb + r) * H + cb;
    float4 v0 = *(const float4*)src, v1 = *(const float4*)(src + 4);
    float vv[8] = {v0.x, v0.y, v0.z, v0.w, v1.x, v1.y, v1.z, v1.w};
    short hv[8], lv[8];
    #pragma unroll
    for (int u = 0; u < 8; u++) {
      unsigned short hb = bf16_rne(vv[u]);
      hv[u] = (short)hb;
      lv[u] = (short)bf16_rne(vv[u] - bf16_to_f(hb));
    }
    *(short8_t*)&sH[r][cb] = *(short8_t*)hv;
    *(short8_t*)&sL[r][cb] = *(short8_t*)lv;
  }
  __syncthreads();
  const int lane = tid & 63, wid = tid >> 6;
  const int quad = lane >> 4, ln = lane & 15;
  const int col0 = wid * 32 + ln;
  f32x4 acc0 = (f32x4){0.f, 0.f, 0.f, 0.f};
  f32x4 acc1 = (f32x4){0.f, 0.f, 0.f, 0.f};
  gemm_tile(sH, sL, pw1, ln, quad, wid, acc0, acc1);
  __syncthreads();
  {
    float ba = b1[col0], bb = b1[col0 + 16];
    #pragma unroll
    for (int reg = 0; reg < 4; reg++) {
      int row = quad * 4 + reg;
      float v0 = ssp_f(acc0[reg] + ba);
      float v1 = ssp_f(acc1[reg] + bb);
      unsigned short h0 = bf16_rne(v0), h1 = bf16_rne(v1);
      sH[row][col0] = (short)h0;
      sL[row][col0] = (short)bf16_rne(v0 - bf16_to_f(h0));
      sH[row][col0 + 16] = (short)h1;
      sL[row][col0 + 16] = (short)bf16_rne(v1 - bf16_to_f(h1));
    }
  }
  __syncthreads();
  acc0 = (f32x4){0.f, 0.f, 0.f, 0.f};
  acc1 = (f32x4){0.f, 0.f, 0.f, 0.f};
  gemm_tile(sH, sL, pw2, ln, quad, wid, acc0, acc1);
  {
    float ba = b2[col0], bb = b2[col0 + 16];
    #pragma unroll
    for (int reg = 0; reg < 4; reg++) {
      int row = quad * 4 + reg;
      size_t g0 = (size_t)(rb + row) * H + col0;
      out[g0] = acc0[reg] + ba;
      out[g0 + 16] = acc1[reg] + bb;
    }
  }
}

// per-mol pooling (256 contiguous atoms) + head MLP
__global__ __launch_bounds__(256) void k_pool_head(const float* __restrict__ h2,
                                                   const float* __restrict__ hw1,
                                                   const float* __restrict__ hb1,
                                                   const float* __restrict__ hw2,
                                                   const float* __restrict__ hb2,
                                                   float* __restrict__ outp) {
  int m = blockIdx.x;
  int c = threadIdx.x & 127;
  int half = threadIdx.x >> 7;
  __shared__ float mol2[2][128];
  __shared__ float q[64];
  const float* base = h2 + (size_t)m * 256 * H;
  float s = 0.f;
  for (int a = half; a < 256; a += 2) s += base[(size_t)a * H + c];
  mol2[half][c] = s;
  __syncthreads();
  if (threadIdx.x < 64) {
    int j = threadIdx.x;
    float qq = hb1[j];
    #pragma unroll 8
    for (int cc = 0; cc < H; cc++) qq += (mol2[0][cc] + mol2[1][cc]) * hw1[cc * 64 + j];
    q[j] = ssp_f(qq);
  }
  __syncthreads();
  if (threadIdx.x == 0) {
    float o = hb2[0];
    for (int j = 0; j < 64; j++) o += q[j] * hw2[j];
    outp[m] = o;
  }
}

extern "C" void kernel_launch(void* const* d_in, const int* in_sizes, int n_in,
                              void* d_out, int out_size, void* d_ws, size_t ws_size,
                              hipStream_t stream) {
  const int*   z       = (const int*)d_in[0];
  const float* pos     = (const float*)d_in[1];
  const int*   eidx    = (const int*)d_in[2];
  const float* emb     = (const float*)d_in[5];
  const float* mlp_w1  = (const float*)d_in[6];
  const float* mlp_b1  = (const float*)d_in[7];
  const float* mlp_w2  = (const float*)d_in[8];
  const float* mlp_b2  = (const float*)d_in[9];
  const float* cf_w1   = (const float*)d_in[10];
  const float* cf_w2   = (const float*)d_in[11];
  const float* cf_b2   = (const float*)d_in[12];
  const float* int_w   = (const float*)d_in[13];
  const float* int_b   = (const float*)d_in[14];
  const float* out_w1  = (const float*)d_in[15];
  const float* out_b1  = (const float*)d_in[16];
  const float* out_w2  = (const float*)d_in[17];
  const float* out_b2  = (const float*)d_in[18];
  const float* head_w1 = (const float*)d_in[19];
  const float* head_b1 = (const float*)d_in[20];
  const float* head_w2 = (const float*)d_in[21];
  const float* head_b2 = (const float*)d_in[22];

  float* ws = (float*)d_ws;
  float*          T    = ws;                                   // 786,432 f
  unsigned short* Tb   = (unsigned short*)(T + 786432);        // 3,145,728 us
  float*          h    = (float*)(Tb + 3145728);               // 2,097,152 f
  float*          h2   = h + 2097152;                          // 2,097,152 f
  unsigned short* xfb0 = (unsigned short*)(h2 + 2097152);      // 2,097,152 us
  unsigned short* xfb1 = xfb0 + 2097152;                       // 2,097,152 us
  int*            pk   = (int*)(xfb1 + 2097152);               // 524,288 i
  short*          PW   = (short*)(pk + 524288);                // 20*32768 s

  k_edge_prep<<<NEDGE / 256, 256, 0, stream>>>(pos, eidx, eidx + NEDGE, pk);
  k_table<<<NL * (TP0 / 2), 256, 0, stream>>>(mlp_w1, mlp_b1, mlp_w2, mlp_b2, T);
  k_prep<<<(20 * 2048) / 256, 256, 0, stream>>>(cf_w1, cf_w2, int_w, out_w1, out_w2, PW);
  k_up<<<(NL * TPB * H) / 256, 256, 0, stream>>>(T, Tb);
  k_init<<<N_ATOMS / 16, 256, 0, stream>>>(z, emb, PW + (size_t)12 * 32768, h, xfb0);

  for (int l = 0; l < NL; l++) {
    unsigned short* xin = (l & 1) ? xfb1 : xfb0;
    unsigned short* xout = (l & 1) ? xfb0 : xfb1;
    const short* pw3 = (l < NL - 1) ? (PW + (size_t)(13 + l) * 32768) : nullptr;
    k_layer<<<N_ATOMS / 16, 256, 0, stream>>>(
        xin, Tb + (size_t)l * TPB * H, pk,
        PW + (size_t)(2 * l) * 32768, cf_b2 + (size_t)l * H,
        PW + (size_t)(2 * l + 1) * 32768, int_b + (size_t)l * H, h, pw3, xout);
  }

  k_readout<<<N_ATOMS / 16, 256, 0, stream>>>(
      h, PW + (size_t)18 * 32768, out_b1, PW + (size_t)19 * 32768, out_b2, h2);
  k_pool_head<<<N_MOL, 256, 0, stream>>>(h2, head_w1, head_b1, head_w2, head_b2,
                                         (float*)d_out);
}

// Round 6
// 310.101 us; speedup vs baseline: 2.7657x; 1.1130x over previous
//
#include <hip/hip_runtime.h>
#include <math.h>

#define N_ATOMS 16384
#define APC 64
#define N_CONF 256
#define N_MOL 64
#define DEG 32
#define NEDGE (N_ATOMS * DEG)
#define H 128
#define G 50
#define NL 6
#define TP0 1024         // fp32 source table points
#define TPB 4096         // bf16 nearest table points
#define CUTOFF 10.0f

typedef __attribute__((ext_vector_type(8))) short short8_t;
typedef __attribute__((ext_vector_type(4))) float f32x4;

__device__ __forceinline__ float ssp_f(float x) {
  return fmaxf(x, 0.f) + log1pf(expf(-fabsf(x))) - 0.69314718055994531f;
}
__device__ __forceinline__ unsigned short bf16_rne(float x) {
  unsigned u = __float_as_uint(x);
  unsigned r = u + 0x7FFF + ((u >> 16) & 1);
  return (unsigned short)(r >> 16);
}
__device__ __forceinline__ float bf16_to_f(unsigned short s) {
  return __uint_as_float(((unsigned)s) << 16);
}
__device__ __forceinline__ float bflo(unsigned u) { return __uint_as_float(u << 16); }
__device__ __forceinline__ float bfhi(unsigned u) { return __uint_as_float(u & 0xFFFF0000u); }

// per-edge: distance -> packed (nearest table index | src_local<<16)
__global__ __launch_bounds__(256) void k_edge_prep(const float* __restrict__ pos,
                                                   const int* __restrict__ esrc,
                                                   const int* __restrict__ etgt,
                                                   int* __restrict__ pk) {
  int e = blockIdx.x * 256 + threadIdx.x;
  int r = esrc[e], c = etgt[e];
  float dx = pos[r * 3 + 0] - pos[c * 3 + 0];
  float dy = pos[r * 3 + 1] - pos[c * 3 + 1];
  float dz = pos[r * 3 + 2] - pos[c * 3 + 2];
  float d = sqrtf(dx * dx + dy * dy + dz * dz);
  int i = (int)(d * ((float)(TPB - 1) / CUTOFF) + 0.5f);
  if (i > TPB - 1) i = TPB - 1;
  if (i < 0) i = 0;
  pk[e] = i | ((r & (APC - 1)) << 16);
}

// fp32 source table T[l][p][c] at TP0 points; 2 points per 256-thread block
__global__ __launch_bounds__(256) void k_table(const float* __restrict__ w1,
                                               const float* __restrict__ b1,
                                               const float* __restrict__ w2,
                                               const float* __restrict__ b2,
                                               float* __restrict__ T) {
  const int l = blockIdx.x >> 9;
  const int grp = threadIdx.x >> 7;
  const int c = threadIdx.x & 127;
  const int p = (blockIdx.x & 511) * 2 + grp;
  const float d = (float)p * (CUTOFF / (float)(TP0 - 1));
  __shared__ float g2[2][64];
  __shared__ float S2[2][128];
  const float gspace = CUTOFF / (float)(G - 1);
  const float coeff = -0.5f / (gspace * gspace);
  if (c < G) {
    float x = d - (float)c * gspace;
    g2[grp][c] = expf(coeff * x * x);
  }
  __syncthreads();
  const float* W1 = w1 + l * G * H;
  float s = b1[l * H + c];
  #pragma unroll 5
  for (int i = 0; i < G; i++) s += g2[grp][i] * W1[i * H + c];
  S2[grp][c] = ssp_f(s);
  __syncthreads();
  const float* W2 = w2 + l * H * H;
  float o = b2[l * H + c];
  #pragma unroll 8
  for (int j = 0; j < H; j++) o += S2[grp][j] * W2[j * H + c];
  float Cc = 0.5f * (cosf(d * (3.14159265358979f / CUTOFF)) + 1.f);
  T[((size_t)l * TP0 + p) * H + c] = o * Cc;
}

// upsample fp32 TP0 table -> bf16 TPB nearest table via lerp
__global__ __launch_bounds__(256) void k_up(const float* __restrict__ T,
                                            unsigned short* __restrict__ Tb) {
  int flat = blockIdx.x * 256 + threadIdx.x;   // < NL*TPB*H
  int l = flat >> 19;
  int rem = flat & 524287;
  int p4 = rem >> 7, c = rem & 127;
  float u = (float)p4 * ((float)(TP0 - 1) / (float)(TPB - 1));
  int i = (int)u;
  if (i > TP0 - 2) i = TP0 - 2;
  float f = u - (float)i;
  const float* Tl = T + ((size_t)l * TP0 + i) * H + c;
  float v = Tl[0] + f * (Tl[H] - Tl[0]);
  Tb[flat] = bf16_rne(v);
}

// Pre-swizzle weights into MFMA B-fragment order (bf16 hi/lo), 16B per thread.
// groups: 0..11 = (cf_w2,int_w) per layer; 12..17 = cf_w1[l]; 18 = out_w1; 19 = out_w2
__global__ __launch_bounds__(256) void k_prep(const float* __restrict__ cf_w1,
                                              const float* __restrict__ cf_w2,
                                              const float* __restrict__ int_w,
                                              const float* __restrict__ out_w1,
                                              const float* __restrict__ out_w2,
                                              short* __restrict__ PW) {
  int e = blockIdx.x * 256 + threadIdx.x;   // < 20*2048
  int g = e >> 11, t = e & 2047;
  int kb = t >> 9, rem = t & 511, nt = rem >> 6, lane = rem & 63;
  int quad = lane >> 4, ln = lane & 15;
  int kbase = kb * 32 + quad * 8;
  int n = nt * 16 + ln;
  const float* src;
  if (g < 12) {
    int l = g >> 1;
    src = (g & 1) ? (int_w + l * 16384) : (cf_w2 + l * 16384);
  } else if (g < 18) {
    src = cf_w1 + (g - 12) * 16384;
  } else {
    src = (g == 18) ? out_w1 : out_w2;
  }
  short hv[8], lv[8];
  #pragma unroll
  for (int j = 0; j < 8; j++) {
    float x = src[(kbase + j) * H + n];
    unsigned short hb = bf16_rne(x);
    hv[j] = (short)hb;
    lv[j] = (short)bf16_rne(x - bf16_to_f(hb));
  }
  size_t base = (size_t)g * 32768 + (size_t)t * 8;
  *(short8_t*)&PW[base] = *(short8_t*)hv;
  *(short8_t*)&PW[base + 16384] = *(short8_t*)lv;
}

#define MFMA(a, b, c) __builtin_amdgcn_mfma_f32_16x16x32_bf16((a), (b), (c), 0, 0, 0)

__device__ __forceinline__ void load_afrags(const short (*AH)[136], const short (*AL)[136],
                                            int rt, int ln, int quad,
                                            short8_t ah[4], short8_t al[4]) {
  #pragma unroll
  for (int kb = 0; kb < 4; kb++) {
    int ko = kb * 32 + quad * 8;
    ah[kb] = *(const short8_t*)&AH[rt * 16 + ln][ko];
    al[kb] = *(const short8_t*)&AL[rt * 16 + ln][ko];
  }
}

__device__ __forceinline__ void gemm4(const short8_t ah[4], const short8_t al[4],
                                      const short* __restrict__ pw, int nt0, int lane,
                                      f32x4 acc[4]) {
  #pragma unroll
  for (int ct = 0; ct < 4; ct++) {
    int nt = nt0 + ct;
    f32x4 a = {0.f, 0.f, 0.f, 0.f};
    #pragma unroll
    for (int kb = 0; kb < 4; kb++) {
      const short* pb = pw + ((size_t)(kb * 8 + nt) * 64 + lane) * 8;
      short8_t bh = *(const short8_t*)pb;
      short8_t bl = *(const short8_t*)(pb + 16384);
      a = MFMA(ah[kb], bh, a);
      a = MFMA(ah[kb], bl, a);
      a = MFMA(al[kb], bh, a);
    }
    acc[ct] = a;
  }
}

// Persistent per-conformer kernel: init + 6 layers + readout + conformer pool.
// block = 1 conformer (64 atoms), 512 threads (8 waves); grid = N_CONF.
__global__ __launch_bounds__(512) void k_mega(
    const int* __restrict__ z, const float* __restrict__ emb,
    const int* __restrict__ pk, const unsigned short* __restrict__ Tb,
    const short* __restrict__ PW, const float* __restrict__ cf_b2,
    const float* __restrict__ int_b, const float* __restrict__ out_b1,
    const float* __restrict__ out_b2, float* __restrict__ conf_emb) {
  __shared__ float xs[64][132];                       // xf, fp32
  __shared__ __align__(16) short hH[64][136], hL[64][136];   // h, bf16 hi/lo
  __shared__ __align__(16) short S1H[64][136], S1L[64][136]; // agg / t scratch
  __shared__ int pks[2048];
  __shared__ float ps[4][128];
  const int conf = blockIdx.x;
  const int tid = threadIdx.x;
  const int lane = tid & 63, w = tid >> 6;
  const int quad = lane >> 4, ln = lane & 15;
  const int rt = w & 3, nt0 = (w >> 2) * 4;
  const int eg = lane >> 4, ch0 = (lane & 15) * 8;

  // edge records (persistent across layers)
  #pragma unroll
  for (int i = 0; i < 4; i++) pks[i * 512 + tid] = pk[conf * 2048 + i * 512 + tid];

  // init h from emb
  {
    int r = tid >> 3, cb = (tid & 7) * 16;
    const float* src = emb + (size_t)z[conf * 64 + r] * H + cb;
    float vv[16];
    #pragma unroll
    for (int q = 0; q < 4; q++) {
      float4 v = *(const float4*)(src + q * 4);
      vv[q * 4 + 0] = v.x; vv[q * 4 + 1] = v.y; vv[q * 4 + 2] = v.z; vv[q * 4 + 3] = v.w;
    }
    short hv[16], lv[16];
    #pragma unroll
    for (int u = 0; u < 16; u++) {
      unsigned short hb = bf16_rne(vv[u]);
      hv[u] = (short)hb;
      lv[u] = (short)bf16_rne(vv[u] - bf16_to_f(hb));
    }
    *(short8_t*)&hH[r][cb] = *(short8_t*)&hv[0];
    *(short8_t*)&hH[r][cb + 8] = *(short8_t*)&hv[8];
    *(short8_t*)&hL[r][cb] = *(short8_t*)&lv[0];
    *(short8_t*)&hL[r][cb + 8] = *(short8_t*)&lv[8];
  }
  __syncthreads();

  // xs0 = h @ cf_w1[0]
  {
    short8_t ah[4], al_[4];
    load_afrags(hH, hL, rt, ln, quad, ah, al_);
    f32x4 acc[4];
    gemm4(ah, al_, PW + (size_t)12 * 32768, nt0, lane, acc);
    #pragma unroll
    for (int ct = 0; ct < 4; ct++)
      #pragma unroll
      for (int reg = 0; reg < 4; reg++)
        xs[rt * 16 + quad * 4 + reg][(nt0 + ct) * 16 + ln] = acc[ct][reg];
  }
  __syncthreads();

  for (int l = 0; l < NL; l++) {
    const unsigned short* Tl = Tb + (size_t)l * TPB * H;
    // ---- aggregation: S1 = split( sum_e T[idx_e] * xs[src_e] ) ----
    for (int aa = 0; aa < 8; aa++) {
      int a2 = w * 8 + aa;
      float acc[8] = {};
      #pragma unroll
      for (int it = 0; it < 8; it++) {
        int m = pks[a2 * DEG + it * 4 + eg];
        int idx = m & 0xFFFF, sl = m >> 16;
        uint4 tv = *(const uint4*)&Tl[(size_t)idx * H + ch0];
        float4 x0 = *(const float4*)&xs[sl][ch0];
        float4 x1 = *(const float4*)&xs[sl][ch0 + 4];
        acc[0] += bflo(tv.x) * x0.x; acc[1] += bfhi(tv.x) * x0.y;
        acc[2] += bflo(tv.y) * x0.z; acc[3] += bfhi(tv.y) * x0.w;
        acc[4] += bflo(tv.z) * x1.x; acc[5] += bfhi(tv.z) * x1.y;
        acc[6] += bflo(tv.w) * x1.z; acc[7] += bfhi(tv.w) * x1.w;
      }
      #pragma unroll
      for (int j = 0; j < 8; j++) {
        acc[j] += __shfl_xor(acc[j], 16);
        acc[j] += __shfl_xor(acc[j], 32);
      }
      if (eg == 0) {
        short hv[8], lv[8];
        #pragma unroll
        for (int j = 0; j < 8; j++) {
          unsigned short hb = bf16_rne(acc[j]);
          hv[j] = (short)hb;
          lv[j] = (short)bf16_rne(acc[j] - bf16_to_f(hb));
        }
        *(short8_t*)&S1H[a2][ch0] = *(short8_t*)hv;
        *(short8_t*)&S1L[a2][ch0] = *(short8_t*)lv;
      }
    }
    __syncthreads();
    // ---- GEMM1: t = ssp(S1 @ cf_w2[l] + cf_b2[l]) -> S1 ----
    {
      short8_t ah[4], al_[4];
      load_afrags(S1H, S1L, rt, ln, quad, ah, al_);
      f32x4 acc[4];
      gemm4(ah, al_, PW + (size_t)(2 * l) * 32768, nt0, lane, acc);
      __syncthreads();
      #pragma unroll
      for (int ct = 0; ct < 4; ct++) {
        int col = (nt0 + ct) * 16 + ln;
        float bb = cf_b2[l * H + col];
        #pragma unroll
        for (int reg = 0; reg < 4; reg++) {
          int row = rt * 16 + quad * 4 + reg;
          float v = ssp_f(acc[ct][reg] + bb);
          unsigned short hb = bf16_rne(v);
          S1H[row][col] = (short)hb;
          S1L[row][col] = (short)bf16_rne(v - bf16_to_f(hb));
        }
      }
    }
    __syncthreads();
    // ---- GEMM2: h += t @ int_w[l] + int_b[l] ----
    {
      short8_t ah[4], al_[4];
      load_afrags(S1H, S1L, rt, ln, quad, ah, al_);
      f32x4 acc[4];
      gemm4(ah, al_, PW + (size_t)(2 * l + 1) * 32768, nt0, lane, acc);
      #pragma unroll
      for (int ct = 0; ct < 4; ct++) {
        int col = (nt0 + ct) * 16 + ln;
        float bb = int_b[l * H + col];
        #pragma unroll
        for (int reg = 0; reg < 4; reg++) {
          int row = rt * 16 + quad * 4 + reg;
          float hv = bf16_to_f((unsigned short)hH[row][col]) +
                     bf16_to_f((unsigned short)hL[row][col]);
          float v = acc[ct][reg] + bb + hv;
          unsigned short hb = bf16_rne(v);
          hH[row][col] = (short)hb;
          hL[row][col] = (short)bf16_rne(v - bf16_to_f(hb));
        }
      }
    }
    __syncthreads();
    // ---- GEMM3: xs = h @ cf_w1[l+1] ----
    if (l < NL - 1) {
      short8_t ah[4], al_[4];
      load_afrags(hH, hL, rt, ln, quad, ah, al_);
      f32x4 acc[4];
      gemm4(ah, al_, PW + (size_t)(13 + l) * 32768, nt0, lane, acc);
      #pragma unroll
      for (int ct = 0; ct < 4; ct++)
        #pragma unroll
        for (int reg = 0; reg < 4; reg++)
          xs[rt * 16 + quad * 4 + reg][(nt0 + ct) * 16 + ln] = acc[ct][reg];
      __syncthreads();
    }
  }

  // ---- readout GEMM1: S1 = ssp(h @ out_w1 + out_b1) ----
  {
    short8_t ah[4], al_[4];
    load_afrags(hH, hL, rt, ln, quad, ah, al_);
    f32x4 acc[4];
    gemm4(ah, al_, PW + (size_t)18 * 32768, nt0, lane, acc);
    __syncthreads();
    #pragma unroll
    for (int ct = 0; ct < 4; ct++) {
      int col = (nt0 + ct) * 16 + ln;
      float bb = out_b1[col];
      #pragma unroll
      for (int reg = 0; reg < 4; reg++) {
        int row = rt * 16 + quad * 4 + reg;
        float v = ssp_f(acc[ct][reg] + bb);
        unsigned short hb = bf16_rne(v);
        S1H[row][col] = (short)hb;
        S1L[row][col] = (short)bf16_rne(v - bf16_to_f(hb));
      }
    }
  }
  __syncthreads();
  // ---- readout GEMM2 + pool: conf_emb[c] = sum_rows (t@out_w2 + out_b2) ----
  {
    short8_t ah[4], al_[4];
    load_afrags(S1H, S1L, rt, ln, quad, ah, al_);
    f32x4 acc[4];
    gemm4(ah, al_, PW + (size_t)19 * 32768, nt0, lane, acc);
    #pragma unroll
    for (int ct = 0; ct < 4; ct++) {
      int col = (nt0 + ct) * 16 + ln;
      float s = acc[ct][0] + acc[ct][1] + acc[ct][2] + acc[ct][3] + 4.f * out_b2[col];
      s += __shfl_xor(s, 16);
      s += __shfl_xor(s, 32);
      if (quad == 0) ps[rt][col] = s;
    }
  }
  __syncthreads();
  if (tid < 128) {
    conf_emb[conf * 128 + tid] =
        ps[0][tid] + ps[1][tid] + ps[2][tid] + ps[3][tid];
  }
}

// mol pooling (4 conformers) + head MLP
__global__ __launch_bounds__(128) void k_pool_head(const float* __restrict__ ce,
                                                   const float* __restrict__ hw1,
                                                   const float* __restrict__ hb1,
                                                   const float* __restrict__ hw2,
                                                   const float* __restrict__ hb2,
                                                   float* __restrict__ outp) {
  int m = blockIdx.x;
  int c = threadIdx.x;
  __shared__ float mol[128];
  __shared__ float q[64];
  const float* base = ce + (size_t)m * 4 * H;
  mol[c] = base[c] + base[H + c] + base[2 * H + c] + base[3 * H + c];
  __syncthreads();
  if (c < 64) {
    float qq = hb1[c];
    #pragma unroll 8
    for (int cc = 0; cc < H; cc++) qq += mol[cc] * hw1[cc * 64 + c];
    q[c] = ssp_f(qq);
  }
  __syncthreads();
  if (c == 0) {
    float o = hb2[0];
    for (int j = 0; j < 64; j++) o += q[j] * hw2[j];
    outp[m] = o;
  }
}

extern "C" void kernel_launch(void* const* d_in, const int* in_sizes, int n_in,
                              void* d_out, int out_size, void* d_ws, size_t ws_size,
                              hipStream_t stream) {
  const int*   z       = (const int*)d_in[0];
  const float* pos     = (const float*)d_in[1];
  const int*   eidx    = (const int*)d_in[2];
  const float* emb     = (const float*)d_in[5];
  const float* mlp_w1  = (const float*)d_in[6];
  const float* mlp_b1  = (const float*)d_in[7];
  const float* mlp_w2  = (const float*)d_in[8];
  const float* mlp_b2  = (const float*)d_in[9];
  const float* cf_w1   = (const float*)d_in[10];
  const float* cf_w2   = (const float*)d_in[11];
  const float* cf_b2   = (const float*)d_in[12];
  const float* int_w   = (const float*)d_in[13];
  const float* int_b   = (const float*)d_in[14];
  const float* out_w1  = (const float*)d_in[15];
  const float* out_b1  = (const float*)d_in[16];
  const float* out_w2  = (const float*)d_in[17];
  const float* out_b2  = (const float*)d_in[18];
  const float* head_w1 = (const float*)d_in[19];
  const float* head_b1 = (const float*)d_in[20];
  const float* head_w2 = (const float*)d_in[21];
  const float* head_b2 = (const float*)d_in[22];

  float* ws = (float*)d_ws;
  float*          T    = ws;                              // 786,432 f
  unsigned short* Tb   = (unsigned short*)(T + 786432);   // 3,145,728 us
  int*            pk   = (int*)(Tb + 3145728);            // 524,288 i
  short*          PW   = (short*)(pk + 524288);           // 655,360 s
  float*          ce   = (float*)(PW + 655360);           // 32,768 f

  k_edge_prep<<<NEDGE / 256, 256, 0, stream>>>(pos, eidx, eidx + NEDGE, pk);
  k_table<<<NL * (TP0 / 2), 256, 0, stream>>>(mlp_w1, mlp_b1, mlp_w2, mlp_b2, T);
  k_prep<<<(20 * 2048) / 256, 256, 0, stream>>>(cf_w1, cf_w2, int_w, out_w1, out_w2, PW);
  k_up<<<(NL * TPB * H) / 256, 256, 0, stream>>>(T, Tb);

  k_mega<<<N_CONF, 512, 0, stream>>>(z, emb, pk, Tb, PW, cf_b2, int_b,
                                     out_b1, out_b2, ce);

  k_pool_head<<<N_MOL, 128, 0, stream>>>(ce, head_w1, head_b1, head_w2, head_b2,
                                         (float*)d_out);
}

// Round 7
// 254.985 us; speedup vs baseline: 3.3635x; 1.2162x over previous
//
#include <hip/hip_runtime.h>
#include <math.h>

#define N_ATOMS 16384
#define APC 64
#define N_CONF 256
#define N_MOL 64
#define DEG 32
#define NEDGE (N_ATOMS * DEG)
#define H 128
#define G 50
#define NL 6
#define TP0 1024         // fp32 source table points
#define TPB 4096         // bf16 nearest table points
#define CUTOFF 10.0f

typedef __attribute__((ext_vector_type(8))) short short8_t;
typedef __attribute__((ext_vector_type(4))) float f32x4;

__device__ __forceinline__ float ssp_f(float x) {
  // softplus(x) - log(2), fast: v_exp_f32 / v_log_f32
  float e = __expf(-fabsf(x));
  return fmaxf(x, 0.f) + __logf(1.f + e) - 0.69314718055994531f;
}
__device__ __forceinline__ unsigned short bf16_rne(float x) {
  unsigned u = __float_as_uint(x);
  unsigned r = u + 0x7FFF + ((u >> 16) & 1);
  return (unsigned short)(r >> 16);
}
__device__ __forceinline__ float bf16_to_f(unsigned short s) {
  return __uint_as_float(((unsigned)s) << 16);
}
__device__ __forceinline__ float bflo(unsigned u) { return __uint_as_float(u << 16); }
__device__ __forceinline__ float bfhi(unsigned u) { return __uint_as_float(u & 0xFFFF0000u); }

// Fused setup: blocks [0,2048) edge prep | [2048,2208) weight prep | [2208,5280) table
__global__ __launch_bounds__(256) void k_setup(
    const float* __restrict__ pos, const int* __restrict__ esrc,
    const int* __restrict__ etgt, int* __restrict__ pk,
    const float* __restrict__ cf_w1, const float* __restrict__ cf_w2,
    const float* __restrict__ int_w, const float* __restrict__ out_w1,
    const float* __restrict__ out_w2, short* __restrict__ PW,
    const float* __restrict__ w1, const float* __restrict__ b1,
    const float* __restrict__ w2, const float* __restrict__ b2,
    float* __restrict__ T) {
  __shared__ float g2[2][64];
  __shared__ float S2[2][128];
  const int b = blockIdx.x;
  const int tid = threadIdx.x;
  if (b < 2048) {
    // ---- edge prep: distance -> packed (table idx | src_local<<16) ----
    int e = b * 256 + tid;
    int r = esrc[e], c = etgt[e];
    float dx = pos[r * 3 + 0] - pos[c * 3 + 0];
    float dy = pos[r * 3 + 1] - pos[c * 3 + 1];
    float dz = pos[r * 3 + 2] - pos[c * 3 + 2];
    float d = sqrtf(dx * dx + dy * dy + dz * dz);
    int i = (int)(d * ((float)(TPB - 1) / CUTOFF) + 0.5f);
    if (i > TPB - 1) i = TPB - 1;
    if (i < 0) i = 0;
    pk[e] = i | ((r & (APC - 1)) << 16);
  } else if (b < 2208) {
    // ---- weight pre-swizzle into MFMA B-fragment order (bf16 hi/lo) ----
    int e = (b - 2048) * 256 + tid;   // < 20*2048
    int g = e >> 11, t = e & 2047;
    int kb = t >> 9, rem = t & 511, nt = rem >> 6, lane = rem & 63;
    int quad = lane >> 4, ln = lane & 15;
    int kbase = kb * 32 + quad * 8;
    int n = nt * 16 + ln;
    const float* src;
    if (g < 12) {
      int l = g >> 1;
      src = (g & 1) ? (int_w + l * 16384) : (cf_w2 + l * 16384);
    } else if (g < 18) {
      src = cf_w1 + (g - 12) * 16384;
    } else {
      src = (g == 18) ? out_w1 : out_w2;
    }
    short hv[8], lv[8];
    #pragma unroll
    for (int j = 0; j < 8; j++) {
      float x = src[(kbase + j) * H + n];
      unsigned short hb = bf16_rne(x);
      hv[j] = (short)hb;
      lv[j] = (short)bf16_rne(x - bf16_to_f(hb));
    }
    size_t base = (size_t)g * 32768 + (size_t)t * 8;
    *(short8_t*)&PW[base] = *(short8_t*)hv;
    *(short8_t*)&PW[base + 16384] = *(short8_t*)lv;
  } else {
    // ---- fp32 filter table at TP0 points; 2 points per block ----
    int bb = b - 2208;
    const int l = bb >> 9;
    const int grp = tid >> 7;
    const int c = tid & 127;
    const int p = (bb & 511) * 2 + grp;
    const float d = (float)p * (CUTOFF / (float)(TP0 - 1));
    const float gspace = CUTOFF / (float)(G - 1);
    const float coeff = -0.5f / (gspace * gspace);
    if (c < G) {
      float x = d - (float)c * gspace;
      g2[grp][c] = __expf(coeff * x * x);
    }
    __syncthreads();
    const float* W1 = w1 + l * G * H;
    float s = b1[l * H + c];
    #pragma unroll 5
    for (int i = 0; i < G; i++) s += g2[grp][i] * W1[i * H + c];
    S2[grp][c] = ssp_f(s);
    __syncthreads();
    const float* W2 = w2 + l * H * H;
    float o = b2[l * H + c];
    #pragma unroll 8
    for (int j = 0; j < H; j++) o += S2[grp][j] * W2[j * H + c];
    float Cc = 0.5f * (__cosf(d * (3.14159265358979f / CUTOFF)) + 1.f);
    T[((size_t)l * TP0 + p) * H + c] = o * Cc;
  }
}

// upsample fp32 TP0 table -> bf16 TPB nearest table via lerp
__global__ __launch_bounds__(256) void k_up(const float* __restrict__ T,
                                            unsigned short* __restrict__ Tb) {
  int flat = blockIdx.x * 256 + threadIdx.x;   // < NL*TPB*H
  int l = flat >> 19;
  int rem = flat & 524287;
  int p4 = rem >> 7, c = rem & 127;
  float u = (float)p4 * ((float)(TP0 - 1) / (float)(TPB - 1));
  int i = (int)u;
  if (i > TP0 - 2) i = TP0 - 2;
  float f = u - (float)i;
  const float* Tl = T + ((size_t)l * TP0 + i) * H + c;
  float v = Tl[0] + f * (Tl[H] - Tl[0]);
  Tb[flat] = bf16_rne(v);
}

#define MFMA(a, b, c) __builtin_amdgcn_mfma_f32_16x16x32_bf16((a), (b), (c), 0, 0, 0)

__device__ __forceinline__ void load_afrags(const short (*AH)[136], const short (*AL)[136],
                                            int rt, int ln, int quad,
                                            short8_t ah[4], short8_t al[4]) {
  #pragma unroll
  for (int kb = 0; kb < 4; kb++) {
    int ko = kb * 32 + quad * 8;
    ah[kb] = *(const short8_t*)&AH[rt * 16 + ln][ko];
    al[kb] = *(const short8_t*)&AL[rt * 16 + ln][ko];
  }
}

// 2 col-tiles per wave
__device__ __forceinline__ void gemm2w(const short8_t ah[4], const short8_t al[4],
                                       const short* __restrict__ pw, int nt0, int lane,
                                       f32x4 acc[2]) {
  #pragma unroll
  for (int ct = 0; ct < 2; ct++) {
    int nt = nt0 + ct;
    f32x4 a = {0.f, 0.f, 0.f, 0.f};
    #pragma unroll
    for (int kb = 0; kb < 4; kb++) {
      const short* pb = pw + ((size_t)(kb * 8 + nt) * 64 + lane) * 8;
      short8_t bh = *(const short8_t*)pb;
      short8_t bl = *(const short8_t*)(pb + 16384);
      a = MFMA(ah[kb], bh, a);
      a = MFMA(ah[kb], bl, a);
      a = MFMA(al[kb], bh, a);
    }
    acc[ct] = a;
  }
}

// Persistent per-conformer kernel: init + 6 layers + readout + conformer pool.
// block = 1 conformer (64 atoms), 1024 threads (16 waves); grid = N_CONF.
__global__ __launch_bounds__(1024) void k_mega(
    const int* __restrict__ z, const float* __restrict__ emb,
    const int* __restrict__ pk, const unsigned short* __restrict__ Tb,
    const short* __restrict__ PW, const float* __restrict__ cf_b2,
    const float* __restrict__ int_b, const float* __restrict__ out_b1,
    const float* __restrict__ out_b2, float* __restrict__ conf_emb) {
  __shared__ float xs[64][132];                               // xf, fp32
  __shared__ __align__(16) short hH[64][136], hL[64][136];    // h, bf16 hi/lo
  __shared__ __align__(16) short S1H[64][136], S1L[64][136];  // agg / t scratch
  __shared__ int pks[2048];
  __shared__ float ps[4][128];
  const int conf = blockIdx.x;
  const int tid = threadIdx.x;
  const int lane = tid & 63, w = tid >> 6;       // 16 waves
  const int quad = lane >> 4, ln = lane & 15;
  const int rt = w & 3, nt0 = (w >> 2) * 2;      // 4 row-tiles x 4 col-groups(2 tiles)
  const int eg = lane >> 4, ch0 = (lane & 15) * 8;

  // edge records (persistent across layers)
  pks[tid] = pk[conf * 2048 + tid];
  pks[tid + 1024] = pk[conf * 2048 + 1024 + tid];

  // init h from emb
  {
    int r = tid >> 4, cb = (tid & 15) * 8;
    const float* src = emb + (size_t)z[conf * 64 + r] * H + cb;
    float4 v0 = *(const float4*)src, v1 = *(const float4*)(src + 4);
    float vv[8] = {v0.x, v0.y, v0.z, v0.w, v1.x, v1.y, v1.z, v1.w};
    short hv[8], lv[8];
    #pragma unroll
    for (int u = 0; u < 8; u++) {
      unsigned short hb = bf16_rne(vv[u]);
      hv[u] = (short)hb;
      lv[u] = (short)bf16_rne(vv[u] - bf16_to_f(hb));
    }
    *(short8_t*)&hH[r][cb] = *(short8_t*)hv;
    *(short8_t*)&hL[r][cb] = *(short8_t*)lv;
  }
  __syncthreads();

  // xs0 = h @ cf_w1[0]
  {
    short8_t ah[4], al_[4];
    load_afrags(hH, hL, rt, ln, quad, ah, al_);
    f32x4 acc[2];
    gemm2w(ah, al_, PW + (size_t)12 * 32768, nt0, lane, acc);
    #pragma unroll
    for (int ct = 0; ct < 2; ct++)
      #pragma unroll
      for (int reg = 0; reg < 4; reg++)
        xs[rt * 16 + quad * 4 + reg][(nt0 + ct) * 16 + ln] = acc[ct][reg];
  }
  __syncthreads();

  for (int l = 0; l < NL; l++) {
    const unsigned short* Tl = Tb + (size_t)l * TPB * H;
    // ---- aggregation: S1 = split( sum_e T[idx_e] * xs[src_e] ) ----
    #pragma unroll
    for (int aa = 0; aa < 4; aa++) {
      int a2 = w * 4 + aa;
      float acc[8] = {};
      #pragma unroll
      for (int it = 0; it < 8; it++) {
        int m = pks[a2 * DEG + it * 4 + eg];
        int idx = m & 0xFFFF, sl = m >> 16;
        uint4 tv = *(const uint4*)&Tl[(size_t)idx * H + ch0];
        float4 x0 = *(const float4*)&xs[sl][ch0];
        float4 x1 = *(const float4*)&xs[sl][ch0 + 4];
        acc[0] += bflo(tv.x) * x0.x; acc[1] += bfhi(tv.x) * x0.y;
        acc[2] += bflo(tv.y) * x0.z; acc[3] += bfhi(tv.y) * x0.w;
        acc[4] += bflo(tv.z) * x1.x; acc[5] += bfhi(tv.z) * x1.y;
        acc[6] += bflo(tv.w) * x1.z; acc[7] += bfhi(tv.w) * x1.w;
      }
      #pragma unroll
      for (int j = 0; j < 8; j++) {
        acc[j] += __shfl_xor(acc[j], 16);
        acc[j] += __shfl_xor(acc[j], 32);
      }
      if (eg == 0) {
        short hv[8], lv[8];
        #pragma unroll
        for (int j = 0; j < 8; j++) {
          unsigned short hb = bf16_rne(acc[j]);
          hv[j] = (short)hb;
          lv[j] = (short)bf16_rne(acc[j] - bf16_to_f(hb));
        }
        *(short8_t*)&S1H[a2][ch0] = *(short8_t*)hv;
        *(short8_t*)&S1L[a2][ch0] = *(short8_t*)lv;
      }
    }
    __syncthreads();
    // ---- GEMM1: t = ssp(S1 @ cf_w2[l] + cf_b2[l]) -> S1 ----
    {
      short8_t ah[4], al_[4];
      load_afrags(S1H, S1L, rt, ln, quad, ah, al_);
      f32x4 acc[2];
      gemm2w(ah, al_, PW + (size_t)(2 * l) * 32768, nt0, lane, acc);
      __syncthreads();
      #pragma unroll
      for (int ct = 0; ct < 2; ct++) {
        int col = (nt0 + ct) * 16 + ln;
        float bb = cf_b2[l * H + col];
        #pragma unroll
        for (int reg = 0; reg < 4; reg++) {
          int row = rt * 16 + quad * 4 + reg;
          float v = ssp_f(acc[ct][reg] + bb);
          unsigned short hb = bf16_rne(v);
          S1H[row][col] = (short)hb;
          S1L[row][col] = (short)bf16_rne(v - bf16_to_f(hb));
        }
      }
    }
    __syncthreads();
    // ---- GEMM2: h += t @ int_w[l] + int_b[l] ----
    {
      short8_t ah[4], al_[4];
      load_afrags(S1H, S1L, rt, ln, quad, ah, al_);
      f32x4 acc[2];
      gemm2w(ah, al_, PW + (size_t)(2 * l + 1) * 32768, nt0, lane, acc);
      #pragma unroll
      for (int ct = 0; ct < 2; ct++) {
        int col = (nt0 + ct) * 16 + ln;
        float bb = int_b[l * H + col];
        #pragma unroll
        for (int reg = 0; reg < 4; reg++) {
          int row = rt * 16 + quad * 4 + reg;
          float hv = bf16_to_f((unsigned short)hH[row][col]) +
                     bf16_to_f((unsigned short)hL[row][col]);
          float v = acc[ct][reg] + bb + hv;
          unsigned short hb = bf16_rne(v);
          hH[row][col] = (short)hb;
          hL[row][col] = (short)bf16_rne(v - bf16_to_f(hb));
        }
      }
    }
    __syncthreads();
    // ---- GEMM3: xs = h @ cf_w1[l+1] ----
    if (l < NL - 1) {
      short8_t ah[4], al_[4];
      load_afrags(hH, hL, rt, ln, quad, ah, al_);
      f32x4 acc[2];
      gemm2w(ah, al_, PW + (size_t)(13 + l) * 32768, nt0, lane, acc);
      #pragma unroll
      for (int ct = 0; ct < 2; ct++)
        #pragma unroll
        for (int reg = 0; reg < 4; reg++)
          xs[rt * 16 + quad * 4 + reg][(nt0 + ct) * 16 + ln] = acc[ct][reg];
      __syncthreads();
    }
  }

  // ---- readout GEMM1: S1 = ssp(h @ out_w1 + out_b1) ----
  {
    short8_t ah[4], al_[4];
    load_afrags(hH, hL, rt, ln, quad, ah, al_);
    f32x4 acc[2];
    gemm2w(ah, al_, PW + (size_t)18 * 32768, nt0, lane, acc);
    __syncthreads();
    #pragma unroll
    for (int ct = 0; ct < 2; ct++) {
      int col = (nt0 + ct) * 16 + ln;
      float bb = out_b1[col];
      #pragma unroll
      for (int reg = 0; reg < 4; reg++) {
        int row = rt * 16 + quad * 4 + reg;
        float v = ssp_f(acc[ct][reg] + bb);
        unsigned short hb = bf16_rne(v);
        S1H[row][col] = (short)hb;
        S1L[row][col] = (short)bf16_rne(v - bf16_to_f(hb));
      }
    }
  }
  __syncthreads();
  // ---- readout GEMM2 + pool: conf_emb[c] = sum_rows (t@out_w2 + out_b2) ----
  {
    short8_t ah[4], al_[4];
    load_afrags(S1H, S1L, rt, ln, quad, ah, al_);
    f32x4 acc[2];
    gemm2w(ah, al_, PW + (size_t)19 * 32768, nt0, lane, acc);
    #pragma unroll
    for (int ct = 0; ct < 2; ct++) {
      int col = (nt0 + ct) * 16 + ln;
      float s = acc[ct][0] + acc[ct][1] + acc[ct][2] + acc[ct][3] + 4.f * out_b2[col];
      s += __shfl_xor(s, 16);
      s += __shfl_xor(s, 32);
      if (quad == 0) ps[rt][col] = s;
    }
  }
  __syncthreads();
  if (tid < 128) {
    conf_emb[conf * 128 + tid] =
        ps[0][tid] + ps[1][tid] + ps[2][tid] + ps[3][tid];
  }
}

// mol pooling (4 conformers) + head MLP
__global__ __launch_bounds__(128) void k_pool_head(const float* __restrict__ ce,
                                                   const float* __restrict__ hw1,
                                                   const float* __restrict__ hb1,
                                                   const float* __restrict__ hw2,
                                                   const float* __restrict__ hb2,
                                                   float* __restrict__ outp) {
  int m = blockIdx.x;
  int c = threadIdx.x;
  __shared__ float mol[128];
  __shared__ float q[64];
  const float* base = ce + (size_t)m * 4 * H;
  mol[c] = base[c] + base[H + c] + base[2 * H + c] + base[3 * H + c];
  __syncthreads();
  if (c < 64) {
    float qq = hb1[c];
    #pragma unroll 8
    for (int cc = 0; cc < H; cc++) qq += mol[cc] * hw1[cc * 64 + c];
    q[c] = ssp_f(qq);
  }
  __syncthreads();
  if (c == 0) {
    float o = hb2[0];
    for (int j = 0; j < 64; j++) o += q[j] * hw2[j];
    outp[m] = o;
  }
}

extern "C" void kernel_launch(void* const* d_in, const int* in_sizes, int n_in,
                              void* d_out, int out_size, void* d_ws, size_t ws_size,
                              hipStream_t stream) {
  const int*   z       = (const int*)d_in[0];
  const float* pos     = (const float*)d_in[1];
  const int*   eidx    = (const int*)d_in[2];
  const float* emb     = (const float*)d_in[5];
  const float* mlp_w1  = (const float*)d_in[6];
  const float* mlp_b1  = (const float*)d_in[7];
  const float* mlp_w2  = (const float*)d_in[8];
  const float* mlp_b2  = (const float*)d_in[9];
  const float* cf_w1   = (const float*)d_in[10];
  const float* cf_w2   = (const float*)d_in[11];
  const float* cf_b2   = (const float*)d_in[12];
  const float* int_w   = (const float*)d_in[13];
  const float* int_b   = (const float*)d_in[14];
  const float* out_w1  = (const float*)d_in[15];
  const float* out_b1  = (const float*)d_in[16];
  const float* out_w2  = (const float*)d_in[17];
  const float* out_b2  = (const float*)d_in[18];
  const float* head_w1 = (const float*)d_in[19];
  const float* head_b1 = (const float*)d_in[20];
  const float* head_w2 = (const float*)d_in[21];
  const float* head_b2 = (const float*)d_in[22];

  float* ws = (float*)d_ws;
  float*          T    = ws;                              // 786,432 f
  unsigned short* Tb   = (unsigned short*)(T + 786432);   // 3,145,728 us
  int*            pk   = (int*)(Tb + 3145728);            // 524,288 i
  short*          PW   = (short*)(pk + 524288);           // 655,360 s
  float*          ce   = (float*)(PW + 655360);           // 32,768 f

  k_setup<<<5280, 256, 0, stream>>>(pos, eidx, eidx + NEDGE, pk,
                                    cf_w1, cf_w2, int_w, out_w1, out_w2, PW,
                                    mlp_w1, mlp_b1, mlp_w2, mlp_b2, T);
  k_up<<<(NL * TPB * H) / 256, 256, 0, stream>>>(T, Tb);

  k_mega<<<N_CONF, 1024, 0, stream>>>(z, emb, pk, Tb, PW, cf_b2, int_b,
                                      out_b1, out_b2, ce);

  k_pool_head<<<N_MOL, 128, 0, stream>>>(ce, head_w1, head_b1, head_w2, head_b2,
                                         (float*)d_out);
}

// Round 8
// 243.075 us; speedup vs baseline: 3.5283x; 1.0490x over previous
//
#include <hip/hip_runtime.h>
#include <math.h>

#define N_ATOMS 16384
#define APC 64
#define N_CONF 256
#define N_MOL 64
#define DEG 32
#define NEDGE (N_ATOMS * DEG)
#define H 128
#define G 50
#define NL 6
#define TP0 512          // fp32 source table points
#define TPB 4096         // bf16 nearest table points
#define CUTOFF 10.0f

typedef __attribute__((ext_vector_type(8))) short short8_t;
typedef __attribute__((ext_vector_type(4))) float f32x4;
typedef __attribute__((ext_vector_type(2))) float f32x2;

__device__ __forceinline__ float ssp_f(float x) {
  float e = __expf(-fabsf(x));
  return fmaxf(x, 0.f) + __logf(1.f + e) - 0.69314718055994531f;
}
__device__ __forceinline__ unsigned short bf16_rne(float x) {
  unsigned u = __float_as_uint(x);
  unsigned r = u + 0x7FFF + ((u >> 16) & 1);
  return (unsigned short)(r >> 16);
}
__device__ __forceinline__ float bf16_to_f(unsigned short s) {
  return __uint_as_float(((unsigned)s) << 16);
}
__device__ __forceinline__ float bflo(unsigned u) { return __uint_as_float(u << 16); }
__device__ __forceinline__ float bfhi(unsigned u) { return __uint_as_float(u & 0xFFFF0000u); }

// Fused setup: [0,2048) edge prep | [2048,2208) weight prep | [2208,3744) fp32 table
__global__ __launch_bounds__(256) void k_setup(
    const float* __restrict__ pos, const int* __restrict__ esrc,
    const int* __restrict__ etgt, int* __restrict__ pk,
    const float* __restrict__ cf_w1, const float* __restrict__ cf_w2,
    const float* __restrict__ int_w, const float* __restrict__ out_w1,
    const float* __restrict__ out_w2, short* __restrict__ PW,
    const float* __restrict__ w1, const float* __restrict__ b1,
    const float* __restrict__ w2, const float* __restrict__ b2,
    float* __restrict__ T, int* __restrict__ cnt) {
  __shared__ float g2[2][64];
  __shared__ float S2[2][128];
  const int b = blockIdx.x;
  const int tid = threadIdx.x;
  if (b == 0 && tid == 0) *cnt = 0;
  if (b < 2048) {
    int e = b * 256 + tid;
    int r = esrc[e], c = etgt[e];
    float dx = pos[r * 3 + 0] - pos[c * 3 + 0];
    float dy = pos[r * 3 + 1] - pos[c * 3 + 1];
    float dz = pos[r * 3 + 2] - pos[c * 3 + 2];
    float d = sqrtf(dx * dx + dy * dy + dz * dz);
    int i = (int)(d * ((float)(TPB - 1) / CUTOFF) + 0.5f);
    if (i > TPB - 1) i = TPB - 1;
    if (i < 0) i = 0;
    // low 20 bits: byte offset of table row (i*256); bits 20+: src local idx
    pk[e] = (i << 8) | ((r & (APC - 1)) << 20);
  } else if (b < 2208) {
    int e = (b - 2048) * 256 + tid;   // < 20*2048
    int g = e >> 11, t = e & 2047;
    int kb = t >> 9, rem = t & 511, nt = rem >> 6, lane = rem & 63;
    int quad = lane >> 4, ln = lane & 15;
    int kbase = kb * 32 + quad * 8;
    int n = nt * 16 + ln;
    const float* src;
    if (g < 12) {
      int l = g >> 1;
      src = (g & 1) ? (int_w + l * 16384) : (cf_w2 + l * 16384);
    } else if (g < 18) {
      src = cf_w1 + (g - 12) * 16384;
    } else {
      src = (g == 18) ? out_w1 : out_w2;
    }
    short hv[8], lv[8];
    #pragma unroll
    for (int j = 0; j < 8; j++) {
      float x = src[(kbase + j) * H + n];
      unsigned short hb = bf16_rne(x);
      hv[j] = (short)hb;
      lv[j] = (short)bf16_rne(x - bf16_to_f(hb));
    }
    size_t base = (size_t)g * 32768 + (size_t)t * 8;
    *(short8_t*)&PW[base] = *(short8_t*)hv;
    *(short8_t*)&PW[base + 16384] = *(short8_t*)lv;
  } else {
    int bb = b - 2208;
    const int l = bb >> 8;               // TP0/2 = 256 blocks/layer
    const int grp = tid >> 7;
    const int c = tid & 127;
    const int p = (bb & 255) * 2 + grp;
    const float d = (float)p * (CUTOFF / (float)(TP0 - 1));
    const float gspace = CUTOFF / (float)(G - 1);
    const float coeff = -0.5f / (gspace * gspace);
    if (c < G) {
      float x = d - (float)c * gspace;
      g2[grp][c] = __expf(coeff * x * x);
    }
    __syncthreads();
    const float* W1 = w1 + l * G * H;
    float s = b1[l * H + c];
    #pragma unroll 5
    for (int i = 0; i < G; i++) s += g2[grp][i] * W1[i * H + c];
    S2[grp][c] = ssp_f(s);
    __syncthreads();
    const float* W2 = w2 + l * H * H;
    float o = b2[l * H + c];
    #pragma unroll 8
    for (int j = 0; j < H; j++) o += S2[grp][j] * W2[j * H + c];
    float Cc = 0.5f * (__cosf(d * (3.14159265358979f / CUTOFF)) + 1.f);
    T[((size_t)l * TP0 + p) * H + c] = o * Cc;
  }
}

// upsample fp32 TP0 table -> bf16 TPB nearest table via lerp; 4 ch per thread
__global__ __launch_bounds__(256) void k_up(const float* __restrict__ T,
                                            unsigned short* __restrict__ Tb) {
  int t = blockIdx.x * 256 + threadIdx.x;   // < NL*TPB*H/4
  int l = t >> 17;                          // TPB*H/4 = 131072
  int rem = t & 131071;
  int p4 = rem >> 5, cg = rem & 31;
  int c = cg * 4;
  float u = (float)p4 * ((float)(TP0 - 1) / (float)(TPB - 1));
  int i = (int)u;
  if (i > TP0 - 2) i = TP0 - 2;
  float f = u - (float)i;
  const float* a = T + ((size_t)l * TP0 + i) * H + c;
  float4 v0 = *(const float4*)a;
  float4 v1 = *(const float4*)(a + H);
  ushort4 o;
  o.x = bf16_rne(v0.x + f * (v1.x - v0.x));
  o.y = bf16_rne(v0.y + f * (v1.y - v0.y));
  o.z = bf16_rne(v0.z + f * (v1.z - v0.z));
  o.w = bf16_rne(v0.w + f * (v1.w - v0.w));
  *(ushort4*)&Tb[((size_t)l * TPB + p4) * H + c] = o;
}

#define MFMA(a, b, c) __builtin_amdgcn_mfma_f32_16x16x32_bf16((a), (b), (c), 0, 0, 0)

// wave handles 2 row-tiles (rt2 half) x 1 col-tile nt; B loaded once per kb.
__device__ __forceinline__ void gemm_rt2(const short (*AH)[136], const short (*AL)[136],
                                         const short* __restrict__ pw,
                                         int rt2, int nt, int lane, int quad, int ln,
                                         f32x4 acc[2]) {
  #pragma unroll
  for (int kb = 0; kb < 4; kb++) {
    const short* pb = pw + ((size_t)(kb * 8 + nt) * 64 + lane) * 8;
    short8_t bh = *(const short8_t*)pb;
    short8_t bl = *(const short8_t*)(pb + 16384);
    int ko = kb * 32 + quad * 8;
    #pragma unroll
    for (int rtt = 0; rtt < 2; rtt++) {
      int row = rt2 * 32 + rtt * 16 + ln;
      short8_t ah = *(const short8_t*)&AH[row][ko];
      short8_t al = *(const short8_t*)&AL[row][ko];
      acc[rtt] = MFMA(ah, bh, acc[rtt]);
      acc[rtt] = MFMA(ah, bl, acc[rtt]);
      acc[rtt] = MFMA(al, bh, acc[rtt]);
    }
  }
}

// Persistent per-conformer kernel + fused mol pool/head in last block.
__global__ __launch_bounds__(1024, 1) void k_mega(
    const int* __restrict__ z, const float* __restrict__ emb,
    const int* __restrict__ pk, const unsigned short* __restrict__ Tb,
    const short* __restrict__ PW, const float* __restrict__ cf_b2,
    const float* __restrict__ int_b, const float* __restrict__ out_b1,
    const float* __restrict__ out_b2, float* __restrict__ ce,
    const float* __restrict__ hw1, const float* __restrict__ hb1,
    const float* __restrict__ hw2, const float* __restrict__ hb2,
    int* __restrict__ cnt, float* __restrict__ outp) {
  __shared__ float xs[64][132];                               // xf, fp32
  __shared__ __align__(16) short hH[64][136], hL[64][136];    // h
  __shared__ __align__(16) short tH[64][136], tL[64][136];    // t
  __shared__ __align__(16) short S1H[64][136], S1L[64][136];  // agg
  __shared__ int pks[2048];
  __shared__ float ps[2][128];
  __shared__ int is_last;
  const int conf = blockIdx.x;
  const int tid = threadIdx.x;
  const int lane = tid & 63, w = tid >> 6;       // 16 waves
  const int quad = lane >> 4, ln = lane & 15;
  const int rt2 = w & 1, nt = w >> 1;            // 2 row-halves x 8 col-tiles
  const int eg = lane >> 4, ch0 = (lane & 15) * 8;

  pks[tid] = pk[conf * 2048 + tid];
  pks[tid + 1024] = pk[conf * 2048 + 1024 + tid];

  // init h from emb
  {
    int r = tid >> 4, cb = (tid & 15) * 8;
    const float* src = emb + (size_t)z[conf * 64 + r] * H + cb;
    float4 v0 = *(const float4*)src, v1 = *(const float4*)(src + 4);
    float vv[8] = {v0.x, v0.y, v0.z, v0.w, v1.x, v1.y, v1.z, v1.w};
    short hv[8], lv[8];
    #pragma unroll
    for (int u = 0; u < 8; u++) {
      unsigned short hb = bf16_rne(vv[u]);
      hv[u] = (short)hb;
      lv[u] = (short)bf16_rne(vv[u] - bf16_to_f(hb));
    }
    *(short8_t*)&hH[r][cb] = *(short8_t*)hv;
    *(short8_t*)&hL[r][cb] = *(short8_t*)lv;
  }
  __syncthreads();

  // xs0 = h @ cf_w1[0]
  {
    f32x4 acc[2] = {{0.f, 0.f, 0.f, 0.f}, {0.f, 0.f, 0.f, 0.f}};
    gemm_rt2(hH, hL, PW + (size_t)12 * 32768, rt2, nt, lane, quad, ln, acc);
    int col = nt * 16 + ln;
    #pragma unroll
    for (int rtt = 0; rtt < 2; rtt++)
      #pragma unroll
      for (int reg = 0; reg < 4; reg++)
        xs[rt2 * 32 + rtt * 16 + quad * 4 + reg][col] = acc[rtt][reg];
  }
  __syncthreads();

  for (int l = 0; l < NL; l++) {
    const char* Tlb = (const char*)(Tb + (size_t)l * TPB * H) + ch0 * 2;
    // ---- aggregation ----
    #pragma unroll 1
    for (int aa = 0; aa < 4; aa++) {
      int a2 = w * 4 + aa;
      int ms[8];
      uint4 tvv[8];
      #pragma unroll
      for (int it = 0; it < 8; it++) {
        ms[it] = pks[a2 * DEG + it * 4 + eg];
        tvv[it] = *(const uint4*)(Tlb + (ms[it] & 0xFFFFF));
      }
      f32x2 ac0 = {0.f, 0.f}, ac1 = {0.f, 0.f}, ac2 = {0.f, 0.f}, ac3 = {0.f, 0.f};
      #pragma unroll
      for (int it = 0; it < 8; it++) {
        int sl = ms[it] >> 20;
        const float* xr = &xs[sl][ch0];
        float4 x0 = *(const float4*)xr;
        float4 x1 = *(const float4*)(xr + 4);
        uint4 tv = tvv[it];
        ac0 = __builtin_elementwise_fma((f32x2){bflo(tv.x), bfhi(tv.x)},
                                        (f32x2){x0.x, x0.y}, ac0);
        ac1 = __builtin_elementwise_fma((f32x2){bflo(tv.y), bfhi(tv.y)},
                                        (f32x2){x0.z, x0.w}, ac1);
        ac2 = __builtin_elementwise_fma((f32x2){bflo(tv.z), bfhi(tv.z)},
                                        (f32x2){x1.x, x1.y}, ac2);
        ac3 = __builtin_elementwise_fma((f32x2){bflo(tv.w), bfhi(tv.w)},
                                        (f32x2){x1.z, x1.w}, ac3);
      }
      float accs[8] = {ac0.x, ac0.y, ac1.x, ac1.y, ac2.x, ac2.y, ac3.x, ac3.y};
      #pragma unroll
      for (int j = 0; j < 8; j++) {
        accs[j] += __shfl_xor(accs[j], 16);
        accs[j] += __shfl_xor(accs[j], 32);
      }
      float va = eg == 0 ? accs[0] : eg == 1 ? accs[2] : eg == 2 ? accs[4] : accs[6];
      float vb = eg == 0 ? accs[1] : eg == 1 ? accs[3] : eg == 2 ? accs[5] : accs[7];
      unsigned short ha = bf16_rne(va), hb = bf16_rne(vb);
      unsigned short la = bf16_rne(va - bf16_to_f(ha));
      unsigned short lb = bf16_rne(vb - bf16_to_f(hb));
      int cw = ch0 + eg * 2;
      *(short2*)&S1H[a2][cw] = make_short2((short)ha, (short)hb);
      *(short2*)&S1L[a2][cw] = make_short2((short)la, (short)lb);
    }
    __syncthreads();
    // ---- GEMM1: t = ssp(S1 @ cf_w2[l] + cf_b2[l]) ----
    {
      f32x4 acc[2] = {{0.f, 0.f, 0.f, 0.f}, {0.f, 0.f, 0.f, 0.f}};
      gemm_rt2(S1H, S1L, PW + (size_t)(2 * l) * 32768, rt2, nt, lane, quad, ln, acc);
      int col = nt * 16 + ln;
      float bb = cf_b2[l * H + col];
      #pragma unroll
      for (int rtt = 0; rtt < 2; rtt++)
        #pragma unroll
        for (int reg = 0; reg < 4; reg++) {
          int row = rt2 * 32 + rtt * 16 + quad * 4 + reg;
          float v = ssp_f(acc[rtt][reg] + bb);
          unsigned short hb = bf16_rne(v);
          tH[row][col] = (short)hb;
          tL[row][col] = (short)bf16_rne(v - bf16_to_f(hb));
        }
    }
    __syncthreads();
    // ---- GEMM2: h += t @ int_w[l] + int_b[l] ----
    {
      f32x4 acc[2] = {{0.f, 0.f, 0.f, 0.f}, {0.f, 0.f, 0.f, 0.f}};
      gemm_rt2(tH, tL, PW + (size_t)(2 * l + 1) * 32768, rt2, nt, lane, quad, ln, acc);
      int col = nt * 16 + ln;
      float bb = int_b[l * H + col];
      #pragma unroll
      for (int rtt = 0; rtt < 2; rtt++)
        #pragma unroll
        for (int reg = 0; reg < 4; reg++) {
          int row = rt2 * 32 + rtt * 16 + quad * 4 + reg;
          float hv = bf16_to_f((unsigned short)hH[row][col]) +
                     bf16_to_f((unsigned short)hL[row][col]);
          float v = acc[rtt][reg] + bb + hv;
          unsigned short hb = bf16_rne(v);
          hH[row][col] = (short)hb;
          hL[row][col] = (short)bf16_rne(v - bf16_to_f(hb));
        }
    }
    __syncthreads();
    // ---- GEMM3: xs = h @ cf_w1[l+1] ----
    if (l < NL - 1) {
      f32x4 acc[2] = {{0.f, 0.f, 0.f, 0.f}, {0.f, 0.f, 0.f, 0.f}};
      gemm_rt2(hH, hL, PW + (size_t)(13 + l) * 32768, rt2, nt, lane, quad, ln, acc);
      int col = nt * 16 + ln;
      #pragma unroll
      for (int rtt = 0; rtt < 2; rtt++)
        #pragma unroll
        for (int reg = 0; reg < 4; reg++)
          xs[rt2 * 32 + rtt * 16 + quad * 4 + reg][col] = acc[rtt][reg];
      __syncthreads();
    }
  }

  // ---- readout GEMM1: t = ssp(h @ out_w1 + out_b1) ----
  {
    f32x4 acc[2] = {{0.f, 0.f, 0.f, 0.f}, {0.f, 0.f, 0.f, 0.f}};
    gemm_rt2(hH, hL, PW + (size_t)18 * 32768, rt2, nt, lane, quad, ln, acc);
    int col = nt * 16 + ln;
    float bb = out_b1[col];
    #pragma unroll
    for (int rtt = 0; rtt < 2; rtt++)
      #pragma unroll
      for (int reg = 0; reg < 4; reg++) {
        int row = rt2 * 32 + rtt * 16 + quad * 4 + reg;
        float v = ssp_f(acc[rtt][reg] + bb);
        unsigned short hb = bf16_rne(v);
        tH[row][col] = (short)hb;
        tL[row][col] = (short)bf16_rne(v - bf16_to_f(hb));
      }
  }
  __syncthreads();
  // ---- readout GEMM2 + row-sum pool ----
  {
    f32x4 acc[2] = {{0.f, 0.f, 0.f, 0.f}, {0.f, 0.f, 0.f, 0.f}};
    gemm_rt2(tH, tL, PW + (size_t)19 * 32768, rt2, nt, lane, quad, ln, acc);
    int col = nt * 16 + ln;
    float s = acc[0][0] + acc[0][1] + acc[0][2] + acc[0][3] +
              acc[1][0] + acc[1][1] + acc[1][2] + acc[1][3];
    s += __shfl_xor(s, 16);
    s += __shfl_xor(s, 32);
    if (quad == 0) ps[rt2][col] = s;
  }
  __syncthreads();
  if (tid < 128) {
    float v = ps[0][tid] + ps[1][tid] + 64.f * out_b2[tid];
    __hip_atomic_store(&ce[conf * 128 + tid], v, __ATOMIC_RELAXED,
                       __HIP_MEMORY_SCOPE_AGENT);
  }
  __syncthreads();
  if (tid == 0) {
    __threadfence();
    int old = __hip_atomic_fetch_add(cnt, 1, __ATOMIC_ACQ_REL,
                                     __HIP_MEMORY_SCOPE_AGENT);
    is_last = (old == N_CONF - 1) ? 1 : 0;
  }
  __syncthreads();
  if (is_last) {
    __threadfence();
    float* mol = &xs[0][0];        // 64*128 region
    for (int t = tid; t < N_MOL * 128; t += 1024) {
      int m = t >> 7, c = t & 127;
      const float* b = ce + (size_t)(m * 4) * 128;
      float s = __hip_atomic_load(&b[c], __ATOMIC_RELAXED, __HIP_MEMORY_SCOPE_AGENT) +
                __hip_atomic_load(&b[128 + c], __ATOMIC_RELAXED, __HIP_MEMORY_SCOPE_AGENT) +
                __hip_atomic_load(&b[256 + c], __ATOMIC_RELAXED, __HIP_MEMORY_SCOPE_AGENT) +
                __hip_atomic_load(&b[384 + c], __ATOMIC_RELAXED, __HIP_MEMORY_SCOPE_AGENT);
      mol[t] = s;
    }
    __syncthreads();
    float* q = (float*)&S1H[0][0];  // 64*64 region
    for (int t = tid; t < N_MOL * 64; t += 1024) {
      int m = t >> 6, j = t & 63;
      float qq = hb1[j];
      #pragma unroll 8
      for (int c = 0; c < H; c++) qq += mol[m * 128 + c] * hw1[c * 64 + j];
      q[t] = ssp_f(qq);
    }
    __syncthreads();
    if (tid < N_MOL) {
      float o = hb2[0];
      #pragma unroll 8
      for (int j = 0; j < 64; j++) o += q[tid * 64 + j] * hw2[j];
      outp[tid] = o;
    }
  }
}

extern "C" void kernel_launch(void* const* d_in, const int* in_sizes, int n_in,
                              void* d_out, int out_size, void* d_ws, size_t ws_size,
                              hipStream_t stream) {
  const int*   z       = (const int*)d_in[0];
  const float* pos     = (const float*)d_in[1];
  const int*   eidx    = (const int*)d_in[2];
  const float* emb     = (const float*)d_in[5];
  const float* mlp_w1  = (const float*)d_in[6];
  const float* mlp_b1  = (const float*)d_in[7];
  const float* mlp_w2  = (const float*)d_in[8];
  const float* mlp_b2  = (const float*)d_in[9];
  const float* cf_w1   = (const float*)d_in[10];
  const float* cf_w2   = (const float*)d_in[11];
  const float* cf_b2   = (const float*)d_in[12];
  const float* int_w   = (const float*)d_in[13];
  const float* int_b   = (const float*)d_in[14];
  const float* out_w1  = (const float*)d_in[15];
  const float* out_b1  = (const float*)d_in[16];
  const float* out_w2  = (const float*)d_in[17];
  const float* out_b2  = (const float*)d_in[18];
  const float* head_w1 = (const float*)d_in[19];
  const float* head_b1 = (const float*)d_in[20];
  const float* head_w2 = (const float*)d_in[21];
  const float* head_b2 = (const float*)d_in[22];

  char* ws = (char*)d_ws;
  float*          T   = (float*)ws;                                  // NL*TP0*H
  unsigned short* Tb  = (unsigned short*)(ws + (size_t)NL * TP0 * H * 4);
  char*           p2  = (char*)Tb + (size_t)NL * TPB * H * 2;
  int*            pk  = (int*)p2;
  short*          PW  = (short*)(p2 + (size_t)NEDGE * 4);
  float*          ce  = (float*)((char*)PW + (size_t)20 * 32768 * 2);
  int*            cnt = (int*)((char*)ce + (size_t)N_CONF * H * 4);

  k_setup<<<3744, 256, 0, stream>>>(pos, eidx, eidx + NEDGE, pk,
                                    cf_w1, cf_w2, int_w, out_w1, out_w2, PW,
                                    mlp_w1, mlp_b1, mlp_w2, mlp_b2, T, cnt);
  k_up<<<(NL * TPB * H / 4) / 256, 256, 0, stream>>>(T, Tb);

  k_mega<<<N_CONF, 1024, 0, stream>>>(z, emb, pk, Tb, PW, cf_b2, int_b,
                                      out_b1, out_b2, ce,
                                      head_w1, head_b1, head_w2, head_b2,
                                      cnt, (float*)d_out);
}